// Round 7
// baseline (299.591 us; speedup 1.0000x reference)
//
#include <hip/hip_runtime.h>
#include <math.h>

#define BB 2
#define TT 2048
#define NH 32
#define NKV 8
#define NROWS 4096

typedef __attribute__((ext_vector_type(4))) float floatx4;
typedef __attribute__((ext_vector_type(8))) short short8;
typedef __attribute__((ext_vector_type(4))) short short4v;
typedef __attribute__((ext_vector_type(2))) unsigned int uint2v;

__device__ __forceinline__ short f2bf(float f) {
    union { float fv; unsigned u; } v; v.fv = f;
    unsigned r = v.u + 0x7FFFu + ((v.u >> 16) & 1u);   // RNE
    return (short)(r >> 16);
}
__device__ __forceinline__ float bf2f(short s) {
    union { float fv; unsigned u; } v;
    v.u = ((unsigned)(unsigned short)s) << 16;
    return v.fv;
}
// packed f32x2 -> bf16x2 (RNE), single VALU op (T12 primitive, gfx950)
__device__ __forceinline__ unsigned cvtpk(float lo, float hi) {
    unsigned r;
    asm("v_cvt_pk_bf16_f32 %0, %1, %2" : "=v"(r) : "v"(lo), "v"(hi));
    return r;
}
__device__ __forceinline__ void gld16(const short* g, short* l) {
    __builtin_amdgcn_global_load_lds((const __attribute__((address_space(1))) void*)g,
                                     (__attribute__((address_space(3))) void*)l, 16, 0, 0);
}

#define STR2_(x) #x
#define STR_(x) STR2_(x)
#define VMWAIT(n) asm volatile("s_waitcnt vmcnt(" STR_(n) ")" ::: "memory")
#define LGKM0 asm volatile("s_waitcnt lgkmcnt(0)" ::: "memory")

// ---------------------------------------------------------------------------
// RoPE cos/sin tables: [2048][32] each
// ---------------------------------------------------------------------------
__global__ void rope_tables(float* __restrict__ cosT, float* __restrict__ sinT)
{
    int idx = blockIdx.x * blockDim.x + threadIdx.x;   // 65536
    int t = idx >> 5, i = idx & 31;
    float ang = (float)t * expf(-0.28782313662f * (float)i);  // 10000^(-i/32)
    float s, c;
    sincosf(ang, &s, &c);
    cosT[idx] = c;
    sinT[idx] = s;
}

// ---------------------------------------------------------------------------
// fp32 -> bf16 elementwise (for x)
// ---------------------------------------------------------------------------
__global__ void convert_bf16(const float* __restrict__ src, short* __restrict__ dst, int n)
{
    int idx = (blockIdx.x * blockDim.x + threadIdx.x) * 8;
    if (idx >= n) return;
    float4 a = *(const float4*)(src + idx);
    float4 b = *(const float4*)(src + idx + 4);
    short8 o;
    o[0] = f2bf(a.x); o[1] = f2bf(a.y); o[2] = f2bf(a.z); o[3] = f2bf(a.w);
    o[4] = f2bf(b.x); o[5] = f2bf(b.y); o[6] = f2bf(b.z); o[7] = f2bf(b.w);
    *(short8*)(dst + idx) = o;
}

// ---------------------------------------------------------------------------
// fp32 [K][N] -> bf16 [N][K] transpose-convert (weights -> B^T layout)
// ---------------------------------------------------------------------------
__global__ __launch_bounds__(256) void transpose_conv(
    const float* __restrict__ src, short* __restrict__ dst, int K, int N)
{
    __shared__ short T[32][34];
    const int tx = threadIdx.x & 31, ty = threadIdx.x >> 5;
    const int i0 = blockIdx.y * 32, j0 = blockIdx.x * 32;
    #pragma unroll
    for (int i = 0; i < 4; ++i)
        T[ty + 8 * i][tx] = f2bf(src[(size_t)(i0 + ty + 8 * i) * N + j0 + tx]);
    __syncthreads();
    #pragma unroll
    for (int i = 0; i < 4; ++i)
        dst[(size_t)(j0 + ty + 8 * i) * K + i0 + tx] = T[tx][ty + 8 * i];
}

// ===========================================================================
// 8-phase GEMM (m201 template ported, verified R6): BK=64 per K-tile,
// 2 K-tiles per iteration, 8 phases/iter; counted vmcnt never drains
// in-loop; T2 read-swizzle via pre-swizzled source column (rule 21).
// ===========================================================================

#define ASCALE 0.18033688011112f   // 0.125 * log2(e)

// ---- qkv: 256x256 tile, acc[8][4], A split in 2 halves --------------------
#define LDAq(CC, mt, ks) (*(short8*)&sA[CC][wm][((mt)*16 + l15)*64 + ((((ks)*4 + quad)^e3)<<3)])
#define LDBq(CC, nt, ks) (*(short8*)&sB[CC][wn>>1][((wn&1)*64 + (nt)*16 + l15)*64 + ((((ks)*4 + quad)^e3)<<3)])

#define STGAq(d, h, kt) { const short* s_ = gA + (size_t)(h)*128*2048 + (size_t)(kt)*64; \
    gld16(s_,                   &sA[d][h][sr*64 + sc8]); \
    gld16(s_ + (size_t)64*2048, &sA[d][h][(sr+64)*64 + sc8]); }
#define STGBq(d, h, kt) { const short* s_ = gB + (size_t)(h)*128*2048 + (size_t)(kt)*64; \
    gld16(s_,                   &sB[d][h][sr*64 + sc8]); \
    gld16(s_ + (size_t)64*2048, &sB[d][h][(sr+64)*64 + sc8]); }

#define PHQ(CC, q, VMW, STG) { \
    short8 a00 = LDAq(CC, 2*(q), 0),   a01 = LDAq(CC, 2*(q), 1); \
    short8 a10 = LDAq(CC, 2*(q)+1, 0), a11 = LDAq(CC, 2*(q)+1, 1); \
    if ((q) == 0) { \
        _Pragma("unroll") for (int nt = 0; nt < 4; ++nt) { \
            bfr[nt][0] = LDBq(CC, nt, 0); bfr[nt][1] = LDBq(CC, nt, 1); } } \
    STG; \
    __builtin_amdgcn_s_barrier(); \
    LGKM0; \
    __builtin_amdgcn_sched_barrier(0); \
    __builtin_amdgcn_s_setprio(1); \
    _Pragma("unroll") for (int nt = 0; nt < 4; ++nt) { \
        acc[2*(q)][nt]   = __builtin_amdgcn_mfma_f32_16x16x32_bf16(a00, bfr[nt][0], acc[2*(q)][nt], 0, 0, 0); \
        acc[2*(q)][nt]   = __builtin_amdgcn_mfma_f32_16x16x32_bf16(a01, bfr[nt][1], acc[2*(q)][nt], 0, 0, 0); \
        acc[2*(q)+1][nt] = __builtin_amdgcn_mfma_f32_16x16x32_bf16(a10, bfr[nt][0], acc[2*(q)+1][nt], 0, 0, 0); \
        acc[2*(q)+1][nt] = __builtin_amdgcn_mfma_f32_16x16x32_bf16(a11, bfr[nt][1], acc[2*(q)+1][nt], 0, 0, 0); } \
    __builtin_amdgcn_s_setprio(0); \
    VMW; \
    __builtin_amdgcn_s_barrier(); \
}

#define NOP_ ((void)0)

// QKV GEMM with fused RoPE. q pre-scaled by ASCALE; v written transposed.
__global__ __launch_bounds__(512) void gemm_qkv(
    const short* __restrict__ A, const short* __restrict__ BT,
    const float* __restrict__ cosT, const float* __restrict__ sinT,
    short* __restrict__ q, short* __restrict__ kout, short* __restrict__ vout)
{
    __shared__ short sA[2][2][128 * 64];   // 64 KB  [dbuf][half][row*64+col]
    __shared__ short sB[2][2][128 * 64];   // 64 KB
    const int tid = threadIdx.x, lane = tid & 63, w = tid >> 6;
    const int l15 = lane & 15, quad = lane >> 4, e3 = l15 & 7;
    const int wm = w >> 2, wn = w & 3;
    const int mBase = blockIdx.y * 256, nBase = blockIdx.x * 256;

    // staging: thread -> (row sr/sr+64, 16B chunk sc); source col pre-swizzled
    const int sr = tid >> 3, sc = tid & 7;
    const int cs = sc ^ (sr & 7);          // involution; (sr+64)&7 == sr&7
    const int sc8 = sc * 8;
    const short* gA = A + (size_t)(mBase + sr) * 2048 + cs * 8;
    const short* gB = BT + (size_t)(nBase + sr) * 2048 + cs * 8;

    floatx4 acc[8][4];
    #pragma unroll
    for (int mt = 0; mt < 8; ++mt)
        #pragma unroll
        for (int nt = 0; nt < 4; ++nt)
            acc[mt][nt] = (floatx4){0.f, 0.f, 0.f, 0.f};
    short8 bfr[4][2];

    // prologue: tile0 (A+B) fully, B(1); A(1) staged at iter0 p0,p1
    STGBq(0, 0, 0) STGBq(0, 1, 0) STGAq(0, 0, 0) STGAq(0, 1, 0)
    STGBq(1, 0, 1) STGBq(1, 1, 1)
    VMWAIT(4);                     // tile0's 8 loads landed; B(1) in flight
    __builtin_amdgcn_s_barrier();

    for (int it = 0; it < 15; ++it) {
        const int E2 = 2 * it + 2, O1 = 2 * it + 1, O2 = 2 * it + 3;
        PHQ(0, 0, NOP_,      STGAq(1, 0, O1))
        PHQ(0, 1, NOP_,      STGAq(1, 1, O1))
        PHQ(0, 2, NOP_,      STGBq(0, 0, E2))
        PHQ(0, 3, VMWAIT(4), STGBq(0, 1, E2))
        PHQ(1, 0, NOP_,      STGAq(0, 0, E2))
        PHQ(1, 1, NOP_,      STGAq(0, 1, E2))
        PHQ(1, 2, NOP_,      STGBq(1, 0, O2))
        PHQ(1, 3, VMWAIT(4), STGBq(1, 1, O2))
    }
    // tail: tiles 30,31; only A(31) left to stage
    PHQ(0, 0, NOP_,      STGAq(1, 0, 31))
    PHQ(0, 1, NOP_,      STGAq(1, 1, 31))
    PHQ(0, 2, NOP_,      NOP_)
    PHQ(0, 3, VMWAIT(0), NOP_)
    PHQ(1, 0, NOP_,      NOP_)
    PHQ(1, 1, NOP_,      NOP_)
    PHQ(1, 2, NOP_,      NOP_)
    PHQ(1, 3, NOP_,      NOP_)

    // ---- epilogue ----
    const int nb = nBase + wn * 64;
    if (nb < 2560) {
        const float rs = (nb < 2048) ? ASCALE : 1.0f;
        #pragma unroll
        for (int mt = 0; mt < 8; ++mt)
            #pragma unroll
            for (int r = 0; r < 4; ++r) {
                const int m = mBase + wm * 128 + mt * 16 + quad * 4 + r;
                const int t = m & (TT - 1);
                #pragma unroll
                for (int ntp = 0; ntp < 2; ++ntp) {
                    const int i = ntp * 16 + l15;
                    const float c = cosT[t * 32 + i] * rs;
                    const float s = sinT[t * 32 + i] * rs;
                    float x1 = acc[mt][ntp][r], x2 = acc[mt][ntp + 2][r];
                    acc[mt][ntp][r]     = x1 * c - x2 * s;
                    acc[mt][ntp + 2][r] = x2 * c + x1 * s;
                }
            }
    }
    if (nb < 2048) {
        #pragma unroll
        for (int mt = 0; mt < 8; ++mt)
            #pragma unroll
            for (int nt = 0; nt < 4; ++nt) {
                const int n = nb + nt * 16 + l15;
                #pragma unroll
                for (int r = 0; r < 4; ++r) {
                    const int m = mBase + wm * 128 + mt * 16 + quad * 4 + r;
                    q[(size_t)m * 2048 + n] = f2bf(acc[mt][nt][r]);
                }
            }
    } else if (nb < 2560) {
        #pragma unroll
        for (int mt = 0; mt < 8; ++mt)
            #pragma unroll
            for (int nt = 0; nt < 4; ++nt) {
                const int n = nb + nt * 16 + l15 - 2048;
                #pragma unroll
                for (int r = 0; r < 4; ++r) {
                    const int m = mBase + wm * 128 + mt * 16 + quad * 4 + r;
                    kout[(size_t)m * 512 + n] = f2bf(acc[mt][nt][r]);
                }
            }
    } else {
        #pragma unroll
        for (int mt = 0; mt < 8; ++mt)
            #pragma unroll
            for (int nt = 0; nt < 4; ++nt) {
                const int d = nb + nt * 16 + l15 - 2560;
                const int kvh2 = d >> 6, dd = d & 63;
                const int mrow = mBase + wm * 128 + mt * 16 + quad * 4;
                const int bb = mrow >> 11, t0 = mrow & 2047;
                short4v pk;
                #pragma unroll
                for (int r = 0; r < 4; ++r) pk[r] = f2bf(acc[mt][nt][r]);
                *(short4v*)(vout + ((size_t)((bb * 8 + kvh2) * 64 + dd)) * 2048 + t0) = pk;
            }
    }
}

// ---- gemm_out: 128x256 tile (grid 8x32 = 256 blocks), acc[4][4] -----------
#define LDAo(CC, mt, ks) (*(short8*)&sA[CC][(wm*64 + (mt)*16 + l15)*64 + ((((ks)*4 + quad)^e3)<<3)])
#define LDBo(CC, nt, ks) (*(short8*)&sB[CC][wn>>1][((wn&1)*64 + (nt)*16 + l15)*64 + ((((ks)*4 + quad)^e3)<<3)])

#define STGAo(d, kt) { const short* s_ = gA + (size_t)(kt)*64; \
    gld16(s_,                   &sA[d][sr*64 + sc8]); \
    gld16(s_ + (size_t)64*2048, &sA[d][(sr+64)*64 + sc8]); }
#define STGBo(d, h, kt) { const short* s_ = gB + (size_t)(h)*128*2048 + (size_t)(kt)*64; \
    gld16(s_,                   &sB[d][h][sr*64 + sc8]); \
    gld16(s_ + (size_t)64*2048, &sB[d][h][(sr+64)*64 + sc8]); }

#define PHO(CC, q, VMW, STG) { \
    short8 a0 = LDAo(CC, q, 0), a1 = LDAo(CC, q, 1); \
    if ((q) == 0) { \
        _Pragma("unroll") for (int nt = 0; nt < 4; ++nt) { \
            bfr[nt][0] = LDBo(CC, nt, 0); bfr[nt][1] = LDBo(CC, nt, 1); } } \
    STG; \
    __builtin_amdgcn_s_barrier(); \
    LGKM0; \
    __builtin_amdgcn_sched_barrier(0); \
    __builtin_amdgcn_s_setprio(1); \
    _Pragma("unroll") for (int nt = 0; nt < 4; ++nt) { \
        acc[q][nt] = __builtin_amdgcn_mfma_f32_16x16x32_bf16(a0, bfr[nt][0], acc[q][nt], 0, 0, 0); \
        acc[q][nt] = __builtin_amdgcn_mfma_f32_16x16x32_bf16(a1, bfr[nt][1], acc[q][nt], 0, 0, 0); } \
    __builtin_amdgcn_s_setprio(0); \
    VMW; \
    __builtin_amdgcn_s_barrier(); \
}

__global__ __launch_bounds__(512) void gemm_out(
    const short* __restrict__ A, const short* __restrict__ BT,
    const float* __restrict__ bias, float* __restrict__ out)
{
    __shared__ short sA[2][128 * 64];      // 32 KB  [dbuf][row*64+col]
    __shared__ short sB[2][2][128 * 64];   // 64 KB
    const int tid = threadIdx.x, lane = tid & 63, w = tid >> 6;
    const int l15 = lane & 15, quad = lane >> 4, e3 = l15 & 7;
    const int wm = w >> 2, wn = w & 3;
    const int mBase = blockIdx.y * 128, nBase = blockIdx.x * 256;

    const int sr = tid >> 3, sc = tid & 7;
    const int cs = sc ^ (sr & 7);
    const int sc8 = sc * 8;
    const short* gA = A + (size_t)(mBase + sr) * 2048 + cs * 8;
    const short* gB = BT + (size_t)(nBase + sr) * 2048 + cs * 8;

    floatx4 acc[4][4];
    #pragma unroll
    for (int mt = 0; mt < 4; ++mt)
        #pragma unroll
        for (int nt = 0; nt < 4; ++nt)
            acc[mt][nt] = (floatx4){0.f, 0.f, 0.f, 0.f};
    short8 bfr[4][2];

    // prologue: B(0), A(0), B(1); A(1) staged at iter0 p0
    STGBo(0, 0, 0) STGBo(0, 1, 0) STGAo(0, 0)
    STGBo(1, 0, 1) STGBo(1, 1, 1)
    VMWAIT(4);
    __builtin_amdgcn_s_barrier();

    for (int it = 0; it < 15; ++it) {
        const int E2 = 2 * it + 2, O1 = 2 * it + 1, O2 = 2 * it + 3;
        PHO(0, 0, NOP_,      STGAo(1, O1))
        PHO(0, 1, NOP_,      STGBo(0, 0, E2))
        PHO(0, 2, NOP_,      STGBo(0, 1, E2))
        PHO(0, 3, VMWAIT(4), NOP_)
        PHO(1, 0, NOP_,      STGAo(0, E2))
        PHO(1, 1, NOP_,      STGBo(1, 0, O2))
        PHO(1, 2, NOP_,      STGBo(1, 1, O2))
        PHO(1, 3, VMWAIT(4), NOP_)
    }
    PHO(0, 0, NOP_,      STGAo(1, 31))
    PHO(0, 1, NOP_,      NOP_)
    PHO(0, 2, NOP_,      NOP_)
    PHO(0, 3, VMWAIT(0), NOP_)
    PHO(1, 0, NOP_,      NOP_)
    PHO(1, 1, NOP_,      NOP_)
    PHO(1, 2, NOP_,      NOP_)
    PHO(1, 3, NOP_,      NOP_)

    #pragma unroll
    for (int mt = 0; mt < 4; ++mt)
        #pragma unroll
        for (int nt = 0; nt < 4; ++nt) {
            const int n = nBase + wn * 64 + nt * 16 + l15;
            const float bv = bias[n];
            #pragma unroll
            for (int r = 0; r < 4; ++r) {
                const int m = mBase + wm * 64 + mt * 16 + quad * 4 + r;
                out[(size_t)m * 2048 + n] = acc[mt][nt][r] + bv;
            }
        }
}

// ---------------------------------------------------------------------------
// Causal GQA flash attention v4:
//  * v3 structure (GQA-shared K/V, swapped QK^T, V pre-transposed, XOR
//    swizzle, cvt_pk, no max-tracking, qt pairing) PLUS:
//  * K/V DOUBLE-BUFFER -> ONE barrier per K-tile (was 2). Staging ds_write
//    of tile t+1 (into buf (t+1)&1) issues inside the compute region of
//    tile t; its vmcnt wait is one full tile old (landed). Race edges:
//    write(t+1,B)->read(t+1,B) covered by barrier(t); read(t-1,B)->
//    write(t+1,B) covered by barrier(t-1). LDS 48->64 KB, still 2 blocks/CU
//    (grid-limited at 512 blocks anyway).
// ---------------------------------------------------------------------------
#define LDH 64

__global__ __launch_bounds__(512, 4) void attn_mfma(
    const short* __restrict__ q, const short* __restrict__ k,
    const short* __restrict__ vT, short* __restrict__ ctx)
{
    __shared__ short Ks[2][64 * LDH];         // 16 KB  [db][key][d]  swizzled
    __shared__ short Vt[2][64 * LDH];         // 16 KB  [db][d][key]  swizzled
    __shared__ short Ps[8 * 32 * LDH];        // 32 KB  per-wave P    swizzled

    const int b = blockIdx.z;
    const int qt = b ? blockIdx.x : 31 - blockIdx.x;   // pair heavy with light
    const int kvh = blockIdx.y;
    const int tid = threadIdx.x;
    const int lane = tid & 63, wave = tid >> 6;
    const int l15 = lane & 15, quad = lane >> 4;
    const int e3 = l15 & 7;
    const int h = kvh * 4 + (wave >> 1);
    const int whalf = wave & 1;
    short* P = &Ps[wave * 32 * LDH];

    const int srow = tid >> 3, schunk = tid & 7;
    const int soff = srow * LDH + ((schunk ^ (srow & 7)) << 3);
    const short* gK = k + ((size_t)(b * TT + srow)) * 512 + kvh * 64 + schunk * 8;
    const short* gV = vT + ((size_t)((b * 8 + kvh) * 64 + srow)) * 2048 + schunk * 8;

    // tile 0 loads (hide under Q load)
    short8 rK = *(const short8*)gK;
    short8 rV = *(const short8*)gV;

    // Q fragments direct to registers (pre-scaled by ASCALE)
    short8 qf[2][2];
    {
        const size_t qrow = (size_t)(b * TT + qt * 64 + whalf * 32);
        #pragma unroll
        for (int tq = 0; tq < 2; ++tq)
            #pragma unroll
            for (int kk = 0; kk < 2; ++kk)
                qf[tq][kk] = *(const short8*)(q + (qrow + tq * 16 + l15) * 2048
                                              + h * 64 + kk * 32 + quad * 8);
    }

    floatx4 oacc[2][4];
    #pragma unroll
    for (int tq = 0; tq < 2; ++tq)
        #pragma unroll
        for (int db = 0; db < 4; ++db)
            oacc[tq][db] = (floatx4){0.f, 0.f, 0.f, 0.f};
    float l_part[2] = {0.f, 0.f};

    const int c0 = (quad ^ e3) << 3;
    const int c1 = ((4 + quad) ^ e3) << 3;

    // prologue: stage tile 0 into buf 0; issue tile 1 loads
    *(short8*)&Ks[0][soff] = rK;
    *(short8*)&Vt[0][soff] = rV;
    if (qt > 0) {
        gK += (size_t)64 * 512;
        gV += 64;
        rK = *(const short8*)gK;
        rV = *(const short8*)gV;
    }
    __syncthreads();

    for (int kt = 0; kt <= qt; ++kt) {
        const int cb = kt & 1;
        if (kt < qt) {                        // stage tile kt+1 into other buf
            *(short8*)&Ks[cb ^ 1][soff] = rK; // vmcnt wait is 1 tile old
            *(short8*)&Vt[cb ^ 1][soff] = rV;
            if (kt + 1 < qt) {                // issue tile kt+2 loads
                gK += (size_t)64 * 512;
                gV += 64;
                rK = *(const short8*)gK;
                rV = *(const short8*)gV;
            }
        }

        // ---- S^T strip = K(64xd) . Q^T : lane holds k = quad*4+r, q = l15
        floatx4 sacc[4][2];
        #pragma unroll
        for (int tk = 0; tk < 4; ++tk)
            #pragma unroll
            for (int tq = 0; tq < 2; ++tq)
                sacc[tk][tq] = (floatx4){0.f, 0.f, 0.f, 0.f};
        __builtin_amdgcn_s_setprio(1);
        #pragma unroll
        for (int tk = 0; tk < 4; ++tk) {
            short8 kf0 = *(short8*)&Ks[cb][(tk * 16 + l15) * LDH + c0];
            short8 kf1 = *(short8*)&Ks[cb][(tk * 16 + l15) * LDH + c1];
            #pragma unroll
            for (int tq = 0; tq < 2; ++tq) {
                sacc[tk][tq] = __builtin_amdgcn_mfma_f32_16x16x32_bf16(kf0, qf[tq][0], sacc[tk][tq], 0, 0, 0);
                sacc[tk][tq] = __builtin_amdgcn_mfma_f32_16x16x32_bf16(kf1, qf[tq][1], sacc[tk][tq], 0, 0, 0);
            }
        }
        __builtin_amdgcn_s_setprio(0);

        if (kt == qt) {
            #pragma unroll
            for (int tk = 0; tk < 4; ++tk)
                #pragma unroll
                for (int tq = 0; tq < 2; ++tq) {
                    const int qloc = whalf * 32 + tq * 16 + l15;
                    #pragma unroll
                    for (int r = 0; r < 4; ++r)
                        if (tk * 16 + quad * 4 + r > qloc) sacc[tk][tq][r] = -INFINITY;
                }
        }

        #pragma unroll
        for (int tk = 0; tk < 4; ++tk)
            #pragma unroll
            for (int tq = 0; tq < 2; ++tq) {
                float p0 = exp2f(sacc[tk][tq][0]);
                float p1 = exp2f(sacc[tk][tq][1]);
                float p2 = exp2f(sacc[tk][tq][2]);
                float p3 = exp2f(sacc[tk][tq][3]);
                l_part[tq] += (p0 + p1) + (p2 + p3);
                unsigned u0 = cvtpk(p0, p1);
                unsigned u1 = cvtpk(p2, p3);
                const int pcol = ((tk * 2 + (quad >> 1)) ^ e3) * 8 + (quad & 1) * 4;
                *(uint2v*)&P[(tq * 16 + l15) * LDH + pcol] = (uint2v){u0, u1};
            }

        short8 pf[2][2];
        #pragma unroll
        for (int tq = 0; tq < 2; ++tq) {
            pf[tq][0] = *(short8*)&P[(tq * 16 + l15) * LDH + c0];
            pf[tq][1] = *(short8*)&P[(tq * 16 + l15) * LDH + c1];
        }
        __builtin_amdgcn_s_setprio(1);
        #pragma unroll
        for (int db = 0; db < 4; ++db) {
            short8 vf0 = *(short8*)&Vt[cb][(db * 16 + l15) * LDH + c0];
            short8 vf1 = *(short8*)&Vt[cb][(db * 16 + l15) * LDH + c1];
            #pragma unroll
            for (int tq = 0; tq < 2; ++tq) {
                oacc[tq][db] = __builtin_amdgcn_mfma_f32_16x16x32_bf16(pf[tq][0], vf0, oacc[tq][db], 0, 0, 0);
                oacc[tq][db] = __builtin_amdgcn_mfma_f32_16x16x32_bf16(pf[tq][1], vf1, oacc[tq][db], 0, 0, 0);
            }
        }
        __builtin_amdgcn_s_setprio(0);

        __syncthreads();                      // single barrier per K-tile
    }

    #pragma unroll
    for (int off = 16; off < 64; off <<= 1) {
        l_part[0] += __shfl_xor(l_part[0], off, 64);
        l_part[1] += __shfl_xor(l_part[1], off, 64);
    }

    #pragma unroll
    for (int tq = 0; tq < 2; ++tq)
        #pragma unroll
        for (int r = 0; r < 4; ++r) {
            const float denom = __shfl(l_part[tq], quad * 4 + r, 64);
            const float inv = 1.0f / denom;
            const int row = qt * 64 + whalf * 32 + tq * 16 + quad * 4 + r;
            #pragma unroll
            for (int db = 0; db < 4; ++db)
                ctx[((size_t)(b * TT + row) * 32 + h) * 64 + db * 16 + l15] =
                    f2bf(oacc[tq][db][r] * inv);
        }
}

extern "C" void kernel_launch(void* const* d_in, const int* in_sizes, int n_in,
                              void* d_out, int out_size, void* d_ws, size_t ws_size,
                              hipStream_t stream) {
    const float* x    = (const float*)d_in[0];
    const float* Wq   = (const float*)d_in[1];
    const float* Wk   = (const float*)d_in[2];
    const float* Wv   = (const float*)d_in[3];
    const float* Wo   = (const float*)d_in[4];
    const float* bout = (const float*)d_in[5];
    float* out = (float*)d_out;

    // workspace (shorts): xb | WqkvT | WoT | qb | kb | vb(T) | ctx | tables
    short* xb    = (short*)d_ws;
    short* WqkvT = xb + (size_t)8388608;
    short* WoT   = WqkvT + (size_t)6291456;
    short* qb    = WoT + (size_t)4194304;
    short* kb    = qb + (size_t)8388608;
    short* vb    = kb + (size_t)2097152;
    short* ctx   = vb + (size_t)2097152;
    float* cosT  = (float*)(ctx + (size_t)8388608);
    float* sinT  = cosT + 65536;

    rope_tables<<<256, 256, 0, stream>>>(cosT, sinT);
    convert_bf16<<<4096, 256, 0, stream>>>(x, xb, 8388608);
    transpose_conv<<<dim3(64, 64), 256, 0, stream>>>(Wq, WqkvT, 2048, 2048);
    transpose_conv<<<dim3(16, 64), 256, 0, stream>>>(Wk, WqkvT + (size_t)2048 * 2048, 2048, 512);
    transpose_conv<<<dim3(16, 64), 256, 0, stream>>>(Wv, WqkvT + (size_t)2560 * 2048, 2048, 512);
    transpose_conv<<<dim3(64, 64), 256, 0, stream>>>(Wo, WoT, 2048, 2048);

    gemm_qkv<<<dim3(12, 16), 512, 0, stream>>>(xb, WqkvT, cosT, sinT, qb, kb, vb);

    attn_mfma<<<dim3(32, 8, 2), 512, 0, stream>>>(qb, kb, vb, ctx);

    gemm_out<<<dim3(8, 32), 512, 0, stream>>>(ctx, WoT, bout, out);
}

// Round 8
// 292.062 us; speedup vs baseline: 1.0258x; 1.0258x over previous
//
#include <hip/hip_runtime.h>
#include <math.h>

#define BB 2
#define TT 2048
#define NH 32
#define NKV 8
#define NROWS 4096

typedef __attribute__((ext_vector_type(4))) float floatx4;
typedef __attribute__((ext_vector_type(8))) short short8;
typedef __attribute__((ext_vector_type(4))) short short4v;
typedef __attribute__((ext_vector_type(2))) unsigned int uint2v;

__device__ __forceinline__ short f2bf(float f) {
    union { float fv; unsigned u; } v; v.fv = f;
    unsigned r = v.u + 0x7FFFu + ((v.u >> 16) & 1u);   // RNE
    return (short)(r >> 16);
}
__device__ __forceinline__ float bf2f(short s) {
    union { float fv; unsigned u; } v;
    v.u = ((unsigned)(unsigned short)s) << 16;
    return v.fv;
}
// packed f32x2 -> bf16x2 (RNE), single VALU op (T12 primitive, gfx950)
__device__ __forceinline__ unsigned cvtpk(float lo, float hi) {
    unsigned r;
    asm("v_cvt_pk_bf16_f32 %0, %1, %2" : "=v"(r) : "v"(lo), "v"(hi));
    return r;
}
__device__ __forceinline__ void gld16(const short* g, short* l) {
    __builtin_amdgcn_global_load_lds((const __attribute__((address_space(1))) void*)g,
                                     (__attribute__((address_space(3))) void*)l, 16, 0, 0);
}

#define STR2_(x) #x
#define STR_(x) STR2_(x)
#define VMWAIT(n) asm volatile("s_waitcnt vmcnt(" STR_(n) ")" ::: "memory")
#define LGKM0 asm volatile("s_waitcnt lgkmcnt(0)" ::: "memory")

// ---------------------------------------------------------------------------
// RoPE cos/sin tables: [2048][32] each
// ---------------------------------------------------------------------------
__global__ void rope_tables(float* __restrict__ cosT, float* __restrict__ sinT)
{
    int idx = blockIdx.x * blockDim.x + threadIdx.x;   // 65536
    int t = idx >> 5, i = idx & 31;
    float ang = (float)t * expf(-0.28782313662f * (float)i);  // 10000^(-i/32)
    float s, c;
    sincosf(ang, &s, &c);
    cosT[idx] = c;
    sinT[idx] = s;
}

// ---------------------------------------------------------------------------
// fp32 -> bf16 elementwise (for x)
// ---------------------------------------------------------------------------
__global__ void convert_bf16(const float* __restrict__ src, short* __restrict__ dst, int n)
{
    int idx = (blockIdx.x * blockDim.x + threadIdx.x) * 8;
    if (idx >= n) return;
    float4 a = *(const float4*)(src + idx);
    float4 b = *(const float4*)(src + idx + 4);
    short8 o;
    o[0] = f2bf(a.x); o[1] = f2bf(a.y); o[2] = f2bf(a.z); o[3] = f2bf(a.w);
    o[4] = f2bf(b.x); o[5] = f2bf(b.y); o[6] = f2bf(b.z); o[7] = f2bf(b.w);
    *(short8*)(dst + idx) = o;
}

// ---------------------------------------------------------------------------
// fp32 [K][N] -> bf16 [N][K] transpose-convert (weights -> B^T layout)
// ---------------------------------------------------------------------------
__global__ __launch_bounds__(256) void transpose_conv(
    const float* __restrict__ src, short* __restrict__ dst, int K, int N)
{
    __shared__ short T[32][34];
    const int tx = threadIdx.x & 31, ty = threadIdx.x >> 5;
    const int i0 = blockIdx.y * 32, j0 = blockIdx.x * 32;
    #pragma unroll
    for (int i = 0; i < 4; ++i)
        T[ty + 8 * i][tx] = f2bf(src[(size_t)(i0 + ty + 8 * i) * N + j0 + tx]);
    __syncthreads();
    #pragma unroll
    for (int i = 0; i < 4; ++i)
        dst[(size_t)(j0 + ty + 8 * i) * K + i0 + tx] = T[tx][ty + 8 * i];
}

// ===========================================================================
// 8-phase GEMM (m201 template ported, verified R6): BK=64 per K-tile,
// 2 K-tiles per iteration, 8 phases/iter; counted vmcnt never drains
// in-loop; T2 read-swizzle via pre-swizzled source column (rule 21).
// ===========================================================================

#define ASCALE 0.18033688011112f   // 0.125 * log2(e)

// ---- qkv: 256x256 tile, acc[8][4], A split in 2 halves --------------------
#define LDAq(CC, mt, ks) (*(short8*)&sA[CC][wm][((mt)*16 + l15)*64 + ((((ks)*4 + quad)^e3)<<3)])
#define LDBq(CC, nt, ks) (*(short8*)&sB[CC][wn>>1][((wn&1)*64 + (nt)*16 + l15)*64 + ((((ks)*4 + quad)^e3)<<3)])

#define STGAq(d, h, kt) { const short* s_ = gA + (size_t)(h)*128*2048 + (size_t)(kt)*64; \
    gld16(s_,                   &sA[d][h][sr*64 + sc8]); \
    gld16(s_ + (size_t)64*2048, &sA[d][h][(sr+64)*64 + sc8]); }
#define STGBq(d, h, kt) { const short* s_ = gB + (size_t)(h)*128*2048 + (size_t)(kt)*64; \
    gld16(s_,                   &sB[d][h][sr*64 + sc8]); \
    gld16(s_ + (size_t)64*2048, &sB[d][h][(sr+64)*64 + sc8]); }

#define PHQ(CC, q, VMW, STG) { \
    short8 a00 = LDAq(CC, 2*(q), 0),   a01 = LDAq(CC, 2*(q), 1); \
    short8 a10 = LDAq(CC, 2*(q)+1, 0), a11 = LDAq(CC, 2*(q)+1, 1); \
    if ((q) == 0) { \
        _Pragma("unroll") for (int nt = 0; nt < 4; ++nt) { \
            bfr[nt][0] = LDBq(CC, nt, 0); bfr[nt][1] = LDBq(CC, nt, 1); } } \
    STG; \
    __builtin_amdgcn_s_barrier(); \
    LGKM0; \
    __builtin_amdgcn_sched_barrier(0); \
    __builtin_amdgcn_s_setprio(1); \
    _Pragma("unroll") for (int nt = 0; nt < 4; ++nt) { \
        acc[2*(q)][nt]   = __builtin_amdgcn_mfma_f32_16x16x32_bf16(a00, bfr[nt][0], acc[2*(q)][nt], 0, 0, 0); \
        acc[2*(q)][nt]   = __builtin_amdgcn_mfma_f32_16x16x32_bf16(a01, bfr[nt][1], acc[2*(q)][nt], 0, 0, 0); \
        acc[2*(q)+1][nt] = __builtin_amdgcn_mfma_f32_16x16x32_bf16(a10, bfr[nt][0], acc[2*(q)+1][nt], 0, 0, 0); \
        acc[2*(q)+1][nt] = __builtin_amdgcn_mfma_f32_16x16x32_bf16(a11, bfr[nt][1], acc[2*(q)+1][nt], 0, 0, 0); } \
    __builtin_amdgcn_s_setprio(0); \
    VMW; \
    __builtin_amdgcn_s_barrier(); \
}

#define NOP_ ((void)0)

// QKV GEMM with fused RoPE. q pre-scaled by ASCALE; v written transposed AND
// key-permuted per 32-key group (zero-shuffle PV: slot 8a+j <- key 4a+j for
// j<4, key 16+4a+(j-4) for j>=4) so attention's PV A-fragments are lane-local.
__global__ __launch_bounds__(512) void gemm_qkv(
    const short* __restrict__ A, const short* __restrict__ BT,
    const float* __restrict__ cosT, const float* __restrict__ sinT,
    short* __restrict__ q, short* __restrict__ kout, short* __restrict__ vout)
{
    __shared__ short sA[2][2][128 * 64];   // 64 KB  [dbuf][half][row*64+col]
    __shared__ short sB[2][2][128 * 64];   // 64 KB
    const int tid = threadIdx.x, lane = tid & 63, w = tid >> 6;
    const int l15 = lane & 15, quad = lane >> 4, e3 = l15 & 7;
    const int wm = w >> 2, wn = w & 3;
    const int mBase = blockIdx.y * 256, nBase = blockIdx.x * 256;

    // staging: thread -> (row sr/sr+64, 16B chunk sc); source col pre-swizzled
    const int sr = tid >> 3, sc = tid & 7;
    const int cs = sc ^ (sr & 7);          // involution; (sr+64)&7 == sr&7
    const int sc8 = sc * 8;
    const short* gA = A + (size_t)(mBase + sr) * 2048 + cs * 8;
    const short* gB = BT + (size_t)(nBase + sr) * 2048 + cs * 8;

    floatx4 acc[8][4];
    #pragma unroll
    for (int mt = 0; mt < 8; ++mt)
        #pragma unroll
        for (int nt = 0; nt < 4; ++nt)
            acc[mt][nt] = (floatx4){0.f, 0.f, 0.f, 0.f};
    short8 bfr[4][2];

    // prologue: tile0 (A+B) fully, B(1); A(1) staged at iter0 p0,p1
    STGBq(0, 0, 0) STGBq(0, 1, 0) STGAq(0, 0, 0) STGAq(0, 1, 0)
    STGBq(1, 0, 1) STGBq(1, 1, 1)
    VMWAIT(4);                     // tile0's 8 loads landed; B(1) in flight
    __builtin_amdgcn_s_barrier();

    for (int it = 0; it < 15; ++it) {
        const int E2 = 2 * it + 2, O1 = 2 * it + 1, O2 = 2 * it + 3;
        PHQ(0, 0, NOP_,      STGAq(1, 0, O1))
        PHQ(0, 1, NOP_,      STGAq(1, 1, O1))
        PHQ(0, 2, NOP_,      STGBq(0, 0, E2))
        PHQ(0, 3, VMWAIT(4), STGBq(0, 1, E2))
        PHQ(1, 0, NOP_,      STGAq(0, 0, E2))
        PHQ(1, 1, NOP_,      STGAq(0, 1, E2))
        PHQ(1, 2, NOP_,      STGBq(1, 0, O2))
        PHQ(1, 3, VMWAIT(4), STGBq(1, 1, O2))
    }
    // tail: tiles 30,31; only A(31) left to stage
    PHQ(0, 0, NOP_,      STGAq(1, 0, 31))
    PHQ(0, 1, NOP_,      STGAq(1, 1, 31))
    PHQ(0, 2, NOP_,      NOP_)
    PHQ(0, 3, VMWAIT(0), NOP_)
    PHQ(1, 0, NOP_,      NOP_)
    PHQ(1, 1, NOP_,      NOP_)
    PHQ(1, 2, NOP_,      NOP_)
    PHQ(1, 3, NOP_,      NOP_)

    // ---- epilogue ----
    const int nb = nBase + wn * 64;
    if (nb < 2560) {
        const float rs = (nb < 2048) ? ASCALE : 1.0f;
        #pragma unroll
        for (int mt = 0; mt < 8; ++mt)
            #pragma unroll
            for (int r = 0; r < 4; ++r) {
                const int m = mBase + wm * 128 + mt * 16 + quad * 4 + r;
                const int t = m & (TT - 1);
                #pragma unroll
                for (int ntp = 0; ntp < 2; ++ntp) {
                    const int i = ntp * 16 + l15;
                    const float c = cosT[t * 32 + i] * rs;
                    const float s = sinT[t * 32 + i] * rs;
                    float x1 = acc[mt][ntp][r], x2 = acc[mt][ntp + 2][r];
                    acc[mt][ntp][r]     = x1 * c - x2 * s;
                    acc[mt][ntp + 2][r] = x2 * c + x1 * s;
                }
            }
    }
    if (nb < 2048) {
        #pragma unroll
        for (int mt = 0; mt < 8; ++mt)
            #pragma unroll
            for (int nt = 0; nt < 4; ++nt) {
                const int n = nb + nt * 16 + l15;
                #pragma unroll
                for (int r = 0; r < 4; ++r) {
                    const int m = mBase + wm * 128 + mt * 16 + quad * 4 + r;
                    q[(size_t)m * 2048 + n] = f2bf(acc[mt][nt][r]);
                }
            }
    } else if (nb < 2560) {
        #pragma unroll
        for (int mt = 0; mt < 8; ++mt)
            #pragma unroll
            for (int nt = 0; nt < 4; ++nt) {
                const int n = nb + nt * 16 + l15 - 2048;
                #pragma unroll
                for (int r = 0; r < 4; ++r) {
                    const int m = mBase + wm * 128 + mt * 16 + quad * 4 + r;
                    kout[(size_t)m * 512 + n] = f2bf(acc[mt][nt][r]);
                }
            }
    } else {
        #pragma unroll
        for (int mt = 0; mt < 8; ++mt)
            #pragma unroll
            for (int nt = 0; nt < 4; ++nt) {
                const int d = nb + nt * 16 + l15 - 2560;
                const int kvh2 = d >> 6, dd = d & 63;
                const int mrow = mBase + wm * 128 + mt * 16 + quad * 4;
                const int bb = mrow >> 11, t0 = mrow & 2047;
                // zero-shuffle-PV permutation: key t0 -> slot (per 32-group)
                const int tl = t0 & 31;
                const int slot = (tl < 16) ? ((tl >> 2) << 3)
                                           : ((((tl - 16) >> 2) << 3) + 4);
                const int t0p = (t0 & ~31) + slot;
                short4v pk;
                #pragma unroll
                for (int r = 0; r < 4; ++r) pk[r] = f2bf(acc[mt][nt][r]);
                *(short4v*)(vout + ((size_t)((bb * 8 + kvh2) * 64 + dd)) * 2048 + t0p) = pk;
            }
    }
}

// ---- gemm_out: 128x256 tile (grid 8x32 = 256 blocks), acc[4][4] -----------
#define LDAo(CC, mt, ks) (*(short8*)&sA[CC][(wm*64 + (mt)*16 + l15)*64 + ((((ks)*4 + quad)^e3)<<3)])
#define LDBo(CC, nt, ks) (*(short8*)&sB[CC][wn>>1][((wn&1)*64 + (nt)*16 + l15)*64 + ((((ks)*4 + quad)^e3)<<3)])

#define STGAo(d, kt) { const short* s_ = gA + (size_t)(kt)*64; \
    gld16(s_,                   &sA[d][sr*64 + sc8]); \
    gld16(s_ + (size_t)64*2048, &sA[d][(sr+64)*64 + sc8]); }
#define STGBo(d, h, kt) { const short* s_ = gB + (size_t)(h)*128*2048 + (size_t)(kt)*64; \
    gld16(s_,                   &sB[d][h][sr*64 + sc8]); \
    gld16(s_ + (size_t)64*2048, &sB[d][h][(sr+64)*64 + sc8]); }

#define PHO(CC, q, VMW, STG) { \
    short8 a0 = LDAo(CC, q, 0), a1 = LDAo(CC, q, 1); \
    if ((q) == 0) { \
        _Pragma("unroll") for (int nt = 0; nt < 4; ++nt) { \
            bfr[nt][0] = LDBo(CC, nt, 0); bfr[nt][1] = LDBo(CC, nt, 1); } } \
    STG; \
    __builtin_amdgcn_s_barrier(); \
    LGKM0; \
    __builtin_amdgcn_sched_barrier(0); \
    __builtin_amdgcn_s_setprio(1); \
    _Pragma("unroll") for (int nt = 0; nt < 4; ++nt) { \
        acc[q][nt] = __builtin_amdgcn_mfma_f32_16x16x32_bf16(a0, bfr[nt][0], acc[q][nt], 0, 0, 0); \
        acc[q][nt] = __builtin_amdgcn_mfma_f32_16x16x32_bf16(a1, bfr[nt][1], acc[q][nt], 0, 0, 0); } \
    __builtin_amdgcn_s_setprio(0); \
    VMW; \
    __builtin_amdgcn_s_barrier(); \
}

__global__ __launch_bounds__(512) void gemm_out(
    const short* __restrict__ A, const short* __restrict__ BT,
    const float* __restrict__ bias, float* __restrict__ out)
{
    __shared__ short sA[2][128 * 64];      // 32 KB  [dbuf][row*64+col]
    __shared__ short sB[2][2][128 * 64];   // 64 KB
    const int tid = threadIdx.x, lane = tid & 63, w = tid >> 6;
    const int l15 = lane & 15, quad = lane >> 4, e3 = l15 & 7;
    const int wm = w >> 2, wn = w & 3;
    const int mBase = blockIdx.y * 128, nBase = blockIdx.x * 256;

    const int sr = tid >> 3, sc = tid & 7;
    const int cs = sc ^ (sr & 7);
    const int sc8 = sc * 8;
    const short* gA = A + (size_t)(mBase + sr) * 2048 + cs * 8;
    const short* gB = BT + (size_t)(nBase + sr) * 2048 + cs * 8;

    floatx4 acc[4][4];
    #pragma unroll
    for (int mt = 0; mt < 4; ++mt)
        #pragma unroll
        for (int nt = 0; nt < 4; ++nt)
            acc[mt][nt] = (floatx4){0.f, 0.f, 0.f, 0.f};
    short8 bfr[4][2];

    // prologue: B(0), A(0), B(1); A(1) staged at iter0 p0
    STGBo(0, 0, 0) STGBo(0, 1, 0) STGAo(0, 0)
    STGBo(1, 0, 1) STGBo(1, 1, 1)
    VMWAIT(4);
    __builtin_amdgcn_s_barrier();

    for (int it = 0; it < 15; ++it) {
        const int E2 = 2 * it + 2, O1 = 2 * it + 1, O2 = 2 * it + 3;
        PHO(0, 0, NOP_,      STGAo(1, O1))
        PHO(0, 1, NOP_,      STGBo(0, 0, E2))
        PHO(0, 2, NOP_,      STGBo(0, 1, E2))
        PHO(0, 3, VMWAIT(4), NOP_)
        PHO(1, 0, NOP_,      STGAo(0, E2))
        PHO(1, 1, NOP_,      STGBo(1, 0, O2))
        PHO(1, 2, NOP_,      STGBo(1, 1, O2))
        PHO(1, 3, VMWAIT(4), NOP_)
    }
    PHO(0, 0, NOP_,      STGAo(1, 31))
    PHO(0, 1, NOP_,      NOP_)
    PHO(0, 2, NOP_,      NOP_)
    PHO(0, 3, VMWAIT(0), NOP_)
    PHO(1, 0, NOP_,      NOP_)
    PHO(1, 1, NOP_,      NOP_)
    PHO(1, 2, NOP_,      NOP_)
    PHO(1, 3, NOP_,      NOP_)

    #pragma unroll
    for (int mt = 0; mt < 4; ++mt)
        #pragma unroll
        for (int nt = 0; nt < 4; ++nt) {
            const int n = nBase + wn * 64 + nt * 16 + l15;
            const float bv = bias[n];
            #pragma unroll
            for (int r = 0; r < 4; ++r) {
                const int m = mBase + wm * 64 + mt * 16 + quad * 4 + r;
                out[(size_t)m * 2048 + n] = acc[mt][nt][r] + bv;
            }
        }
}

// ---------------------------------------------------------------------------
// Causal GQA flash attention v5:
//  * v4 structure (GQA-shared K/V, swapped QK^T, XOR swizzle, cvt_pk,
//    no max-tracking, qt pairing, K/V double-buffer + 1 barrier/tile) PLUS:
//  * ZERO-SHUFFLE PV: V comes key-permuted from gemm_qkv (slot 8a+j <->
//    keys 4a+j / 16+4a+j-4 per 32-group), chosen so the QK^T C-layout's
//    lane-resident keys ARE the PV A-fragment slots. P never touches LDS:
//    no ds_write/ds_read/pcol math/lgkm wait on the PV path. Ps buffer
//    deleted -> LDS 64 KB -> 32 KB.
// ---------------------------------------------------------------------------
#define LDH 64

__global__ __launch_bounds__(512, 4) void attn_mfma(
    const short* __restrict__ q, const short* __restrict__ k,
    const short* __restrict__ vT, short* __restrict__ ctx)
{
    __shared__ short Ks[2][64 * LDH];         // 16 KB  [db][key][d]  swizzled
    __shared__ short Vt[2][64 * LDH];         // 16 KB  [db][d][slot] swizzled

    const int b = blockIdx.z;
    const int qt = b ? blockIdx.x : 31 - blockIdx.x;   // pair heavy with light
    const int kvh = blockIdx.y;
    const int tid = threadIdx.x;
    const int lane = tid & 63, wave = tid >> 6;
    const int l15 = lane & 15, quad = lane >> 4;
    const int e3 = l15 & 7;
    const int h = kvh * 4 + (wave >> 1);
    const int whalf = wave & 1;

    const int srow = tid >> 3, schunk = tid & 7;
    const int soff = srow * LDH + ((schunk ^ (srow & 7)) << 3);
    const short* gK = k + ((size_t)(b * TT + srow)) * 512 + kvh * 64 + schunk * 8;
    const short* gV = vT + ((size_t)((b * 8 + kvh) * 64 + srow)) * 2048 + schunk * 8;

    // tile 0 loads (hide under Q load)
    short8 rK = *(const short8*)gK;
    short8 rV = *(const short8*)gV;

    // Q fragments direct to registers (pre-scaled by ASCALE)
    short8 qf[2][2];
    {
        const size_t qrow = (size_t)(b * TT + qt * 64 + whalf * 32);
        #pragma unroll
        for (int tq = 0; tq < 2; ++tq)
            #pragma unroll
            for (int kk = 0; kk < 2; ++kk)
                qf[tq][kk] = *(const short8*)(q + (qrow + tq * 16 + l15) * 2048
                                              + h * 64 + kk * 32 + quad * 8);
    }

    floatx4 oacc[2][4];
    #pragma unroll
    for (int tq = 0; tq < 2; ++tq)
        #pragma unroll
        for (int db = 0; db < 4; ++db)
            oacc[tq][db] = (floatx4){0.f, 0.f, 0.f, 0.f};
    float l_part[2] = {0.f, 0.f};

    const int c0 = (quad ^ e3) << 3;
    const int c1 = ((4 + quad) ^ e3) << 3;

    // prologue: stage tile 0 into buf 0; issue tile 1 loads
    *(short8*)&Ks[0][soff] = rK;
    *(short8*)&Vt[0][soff] = rV;
    if (qt > 0) {
        gK += (size_t)64 * 512;
        gV += 64;
        rK = *(const short8*)gK;
        rV = *(const short8*)gV;
    }
    __syncthreads();

    for (int kt = 0; kt <= qt; ++kt) {
        const int cb = kt & 1;
        if (kt < qt) {                        // stage tile kt+1 into other buf
            *(short8*)&Ks[cb ^ 1][soff] = rK; // vmcnt wait is 1 tile old
            *(short8*)&Vt[cb ^ 1][soff] = rV;
            if (kt + 1 < qt) {                // issue tile kt+2 loads
                gK += (size_t)64 * 512;
                gV += 64;
                rK = *(const short8*)gK;
                rV = *(const short8*)gV;
            }
        }

        // ---- S^T strip = K(64xd) . Q^T : lane holds k = tk*16+quad*4+r, q = l15
        floatx4 sacc[4][2];
        #pragma unroll
        for (int tk = 0; tk < 4; ++tk)
            #pragma unroll
            for (int tq = 0; tq < 2; ++tq)
                sacc[tk][tq] = (floatx4){0.f, 0.f, 0.f, 0.f};
        __builtin_amdgcn_s_setprio(1);
        #pragma unroll
        for (int tk = 0; tk < 4; ++tk) {
            short8 kf0 = *(short8*)&Ks[cb][(tk * 16 + l15) * LDH + c0];
            short8 kf1 = *(short8*)&Ks[cb][(tk * 16 + l15) * LDH + c1];
            #pragma unroll
            for (int tq = 0; tq < 2; ++tq) {
                sacc[tk][tq] = __builtin_amdgcn_mfma_f32_16x16x32_bf16(kf0, qf[tq][0], sacc[tk][tq], 0, 0, 0);
                sacc[tk][tq] = __builtin_amdgcn_mfma_f32_16x16x32_bf16(kf1, qf[tq][1], sacc[tk][tq], 0, 0, 0);
            }
        }
        __builtin_amdgcn_s_setprio(0);

        if (kt == qt) {
            #pragma unroll
            for (int tk = 0; tk < 4; ++tk)
                #pragma unroll
                for (int tq = 0; tq < 2; ++tq) {
                    const int qloc = whalf * 32 + tq * 16 + l15;
                    #pragma unroll
                    for (int r = 0; r < 4; ++r)
                        if (tk * 16 + quad * 4 + r > qloc) sacc[tk][tq][r] = -INFINITY;
                }
        }

        // ---- P = exp2(S'); accumulate l; A-frags built LANE-LOCALLY
        // (V is key-permuted so lane's own keys are exactly its A-slots)
        #pragma unroll
        for (int tk = 0; tk < 4; ++tk)
            #pragma unroll
            for (int tq = 0; tq < 2; ++tq) {
                float p0 = exp2f(sacc[tk][tq][0]);
                float p1 = exp2f(sacc[tk][tq][1]);
                float p2 = exp2f(sacc[tk][tq][2]);
                float p3 = exp2f(sacc[tk][tq][3]);
                l_part[tq] += (p0 + p1) + (p2 + p3);
                sacc[tk][tq][0] = p0; sacc[tk][tq][1] = p1;
                sacc[tk][tq][2] = p2; sacc[tk][tq][3] = p3;
            }
        short8 pf[2][2];
        #pragma unroll
        for (int tq = 0; tq < 2; ++tq)
            #pragma unroll
            for (int g = 0; g < 2; ++g) {
                union { short8 s; unsigned u[4]; } uf;
                uf.u[0] = cvtpk(sacc[2 * g][tq][0],     sacc[2 * g][tq][1]);
                uf.u[1] = cvtpk(sacc[2 * g][tq][2],     sacc[2 * g][tq][3]);
                uf.u[2] = cvtpk(sacc[2 * g + 1][tq][0], sacc[2 * g + 1][tq][1]);
                uf.u[3] = cvtpk(sacc[2 * g + 1][tq][2], sacc[2 * g + 1][tq][3]);
                pf[tq][g] = uf.s;
            }

        // ---- O += P . V   (A = lane-local P frags, B = permuted V^T rows)
        __builtin_amdgcn_s_setprio(1);
        #pragma unroll
        for (int db = 0; db < 4; ++db) {
            short8 vf0 = *(short8*)&Vt[cb][(db * 16 + l15) * LDH + c0];
            short8 vf1 = *(short8*)&Vt[cb][(db * 16 + l15) * LDH + c1];
            #pragma unroll
            for (int tq = 0; tq < 2; ++tq) {
                oacc[tq][db] = __builtin_amdgcn_mfma_f32_16x16x32_bf16(pf[tq][0], vf0, oacc[tq][db], 0, 0, 0);
                oacc[tq][db] = __builtin_amdgcn_mfma_f32_16x16x32_bf16(pf[tq][1], vf1, oacc[tq][db], 0, 0, 0);
            }
        }
        __builtin_amdgcn_s_setprio(0);

        __syncthreads();                      // single barrier per K-tile
    }

    #pragma unroll
    for (int off = 16; off < 64; off <<= 1) {
        l_part[0] += __shfl_xor(l_part[0], off, 64);
        l_part[1] += __shfl_xor(l_part[1], off, 64);
    }

    #pragma unroll
    for (int tq = 0; tq < 2; ++tq)
        #pragma unroll
        for (int r = 0; r < 4; ++r) {
            const float denom = __shfl(l_part[tq], quad * 4 + r, 64);
            const float inv = 1.0f / denom;
            const int row = qt * 64 + whalf * 32 + tq * 16 + quad * 4 + r;
            #pragma unroll
            for (int db = 0; db < 4; ++db)
                ctx[((size_t)(b * TT + row) * 32 + h) * 64 + db * 16 + l15] =
                    f2bf(oacc[tq][db][r] * inv);
        }
}

extern "C" void kernel_launch(void* const* d_in, const int* in_sizes, int n_in,
                              void* d_out, int out_size, void* d_ws, size_t ws_size,
                              hipStream_t stream) {
    const float* x    = (const float*)d_in[0];
    const float* Wq   = (const float*)d_in[1];
    const float* Wk   = (const float*)d_in[2];
    const float* Wv   = (const float*)d_in[3];
    const float* Wo   = (const float*)d_in[4];
    const float* bout = (const float*)d_in[5];
    float* out = (float*)d_out;

    // workspace (shorts): xb | WqkvT | WoT | qb | kb | vb(T) | ctx | tables
    short* xb    = (short*)d_ws;
    short* WqkvT = xb + (size_t)8388608;
    short* WoT   = WqkvT + (size_t)6291456;
    short* qb    = WoT + (size_t)4194304;
    short* kb    = qb + (size_t)8388608;
    short* vb    = kb + (size_t)2097152;
    short* ctx   = vb + (size_t)2097152;
    float* cosT  = (float*)(ctx + (size_t)8388608);
    float* sinT  = cosT + 65536;

    rope_tables<<<256, 256, 0, stream>>>(cosT, sinT);
    convert_bf16<<<4096, 256, 0, stream>>>(x, xb, 8388608);
    transpose_conv<<<dim3(64, 64), 256, 0, stream>>>(Wq, WqkvT, 2048, 2048);
    transpose_conv<<<dim3(16, 64), 256, 0, stream>>>(Wk, WqkvT + (size_t)2048 * 2048, 2048, 512);
    transpose_conv<<<dim3(16, 64), 256, 0, stream>>>(Wv, WqkvT + (size_t)2560 * 2048, 2048, 512);
    transpose_conv<<<dim3(64, 64), 256, 0, stream>>>(Wo, WoT, 2048, 2048);

    gemm_qkv<<<dim3(12, 16), 512, 0, stream>>>(xb, WqkvT, cosT, sinT, qb, kb, vb);

    attn_mfma<<<dim3(32, 8, 2), 512, 0, stream>>>(qb, kb, vb, ctx);

    gemm_out<<<dim3(8, 32), 512, 0, stream>>>(ctx, WoT, bout, out);
}

// Round 10
// 280.143 us; speedup vs baseline: 1.0694x; 1.0425x over previous
//
#include <hip/hip_runtime.h>
#include <math.h>

#define BB 2
#define TT 2048
#define NH 32
#define NKV 8
#define NROWS 4096

typedef __attribute__((ext_vector_type(4))) float floatx4;
typedef __attribute__((ext_vector_type(8))) short short8;
typedef __attribute__((ext_vector_type(4))) short short4v;
typedef __attribute__((ext_vector_type(2))) unsigned int uint2v;

__device__ __forceinline__ short f2bf(float f) {
    union { float fv; unsigned u; } v; v.fv = f;
    unsigned r = v.u + 0x7FFFu + ((v.u >> 16) & 1u);   // RNE
    return (short)(r >> 16);
}
__device__ __forceinline__ float bf2f(short s) {
    union { float fv; unsigned u; } v;
    v.u = ((unsigned)(unsigned short)s) << 16;
    return v.fv;
}
// packed f32x2 -> bf16x2 (RNE), single VALU op (T12 primitive, gfx950)
__device__ __forceinline__ unsigned cvtpk(float lo, float hi) {
    unsigned r;
    asm("v_cvt_pk_bf16_f32 %0, %1, %2" : "=v"(r) : "v"(lo), "v"(hi));
    return r;
}
__device__ __forceinline__ void gld16(const short* g, short* l) {
    __builtin_amdgcn_global_load_lds((const __attribute__((address_space(1))) void*)g,
                                     (__attribute__((address_space(3))) void*)l, 16, 0, 0);
}

#define STR2_(x) #x
#define STR_(x) STR2_(x)
#define VMWAIT(n) asm volatile("s_waitcnt vmcnt(" STR_(n) ")" ::: "memory")
#define LGKM0 asm volatile("s_waitcnt lgkmcnt(0)" ::: "memory")

// ---------------------------------------------------------------------------
// RoPE cos/sin tables: [2048][32] each
// ---------------------------------------------------------------------------
__global__ void rope_tables(float* __restrict__ cosT, float* __restrict__ sinT)
{
    int idx = blockIdx.x * blockDim.x + threadIdx.x;   // 65536
    int t = idx >> 5, i = idx & 31;
    float ang = (float)t * expf(-0.28782313662f * (float)i);  // 10000^(-i/32)
    float s, c;
    sincosf(ang, &s, &c);
    cosT[idx] = c;
    sinT[idx] = s;
}

// ---------------------------------------------------------------------------
// fp32 -> bf16 elementwise (for x)
// ---------------------------------------------------------------------------
__global__ void convert_bf16(const float* __restrict__ src, short* __restrict__ dst, int n)
{
    int idx = (blockIdx.x * blockDim.x + threadIdx.x) * 8;
    if (idx >= n) return;
    float4 a = *(const float4*)(src + idx);
    float4 b = *(const float4*)(src + idx + 4);
    short8 o;
    o[0] = f2bf(a.x); o[1] = f2bf(a.y); o[2] = f2bf(a.z); o[3] = f2bf(a.w);
    o[4] = f2bf(b.x); o[5] = f2bf(b.y); o[6] = f2bf(b.z); o[7] = f2bf(b.w);
    *(short8*)(dst + idx) = o;
}

// ---------------------------------------------------------------------------
// fp32 [K][N] -> bf16 [N][K] transpose-convert (weights -> B^T layout)
// ---------------------------------------------------------------------------
__global__ __launch_bounds__(256) void transpose_conv(
    const float* __restrict__ src, short* __restrict__ dst, int K, int N)
{
    __shared__ short T[32][34];
    const int tx = threadIdx.x & 31, ty = threadIdx.x >> 5;
    const int i0 = blockIdx.y * 32, j0 = blockIdx.x * 32;
    #pragma unroll
    for (int i = 0; i < 4; ++i)
        T[ty + 8 * i][tx] = f2bf(src[(size_t)(i0 + ty + 8 * i) * N + j0 + tx]);
    __syncthreads();
    #pragma unroll
    for (int i = 0; i < 4; ++i)
        dst[(size_t)(j0 + ty + 8 * i) * K + i0 + tx] = T[tx][ty + 8 * i];
}

// ===========================================================================
// 8-phase GEMM (m201 template ported, verified R6): BK=64 per K-tile,
// 2 K-tiles per iteration, 8 phases/iter; counted vmcnt never drains
// in-loop; T2 read-swizzle via pre-swizzled source column (rule 21).
// ===========================================================================

// softmax scale folded into Q, NATURAL-exp domain: 1/sqrt(d) = 1/8 exactly.
// attention uses __expf (native v_exp path, compiler-managed hazards).
#define ASCALE 0.125f

// ---- qkv: 256x256 tile, acc[8][4], A split in 2 halves --------------------
#define LDAq(CC, mt, ks) (*(short8*)&sA[CC][wm][((mt)*16 + l15)*64 + ((((ks)*4 + quad)^e3)<<3)])
#define LDBq(CC, nt, ks) (*(short8*)&sB[CC][wn>>1][((wn&1)*64 + (nt)*16 + l15)*64 + ((((ks)*4 + quad)^e3)<<3)])

#define STGAq(d, h, kt) { const short* s_ = gA + (size_t)(h)*128*2048 + (size_t)(kt)*64; \
    gld16(s_,                   &sA[d][h][sr*64 + sc8]); \
    gld16(s_ + (size_t)64*2048, &sA[d][h][(sr+64)*64 + sc8]); }
#define STGBq(d, h, kt) { const short* s_ = gB + (size_t)(h)*128*2048 + (size_t)(kt)*64; \
    gld16(s_,                   &sB[d][h][sr*64 + sc8]); \
    gld16(s_ + (size_t)64*2048, &sB[d][h][(sr+64)*64 + sc8]); }

#define PHQ(CC, q, VMW, STG) { \
    short8 a00 = LDAq(CC, 2*(q), 0),   a01 = LDAq(CC, 2*(q), 1); \
    short8 a10 = LDAq(CC, 2*(q)+1, 0), a11 = LDAq(CC, 2*(q)+1, 1); \
    if ((q) == 0) { \
        _Pragma("unroll") for (int nt = 0; nt < 4; ++nt) { \
            bfr[nt][0] = LDBq(CC, nt, 0); bfr[nt][1] = LDBq(CC, nt, 1); } } \
    STG; \
    __builtin_amdgcn_s_barrier(); \
    LGKM0; \
    __builtin_amdgcn_sched_barrier(0); \
    __builtin_amdgcn_s_setprio(1); \
    _Pragma("unroll") for (int nt = 0; nt < 4; ++nt) { \
        acc[2*(q)][nt]   = __builtin_amdgcn_mfma_f32_16x16x32_bf16(a00, bfr[nt][0], acc[2*(q)][nt], 0, 0, 0); \
        acc[2*(q)][nt]   = __builtin_amdgcn_mfma_f32_16x16x32_bf16(a01, bfr[nt][1], acc[2*(q)][nt], 0, 0, 0); \
        acc[2*(q)+1][nt] = __builtin_amdgcn_mfma_f32_16x16x32_bf16(a10, bfr[nt][0], acc[2*(q)+1][nt], 0, 0, 0); \
        acc[2*(q)+1][nt] = __builtin_amdgcn_mfma_f32_16x16x32_bf16(a11, bfr[nt][1], acc[2*(q)+1][nt], 0, 0, 0); } \
    __builtin_amdgcn_s_setprio(0); \
    VMW; \
    __builtin_amdgcn_s_barrier(); \
}

#define NOP_ ((void)0)

// QKV GEMM with fused RoPE. q pre-scaled by ASCALE; v written transposed AND
// key-permuted per 32-key group (zero-shuffle PV: slot 8a+j <- key 4a+j for
// j<4, key 16+4a+(j-4) for j>=4) so attention's PV A-fragments are lane-local.
__global__ __launch_bounds__(512) void gemm_qkv(
    const short* __restrict__ A, const short* __restrict__ BT,
    const float* __restrict__ cosT, const float* __restrict__ sinT,
    short* __restrict__ q, short* __restrict__ kout, short* __restrict__ vout)
{
    __shared__ short sA[2][2][128 * 64];   // 64 KB  [dbuf][half][row*64+col]
    __shared__ short sB[2][2][128 * 64];   // 64 KB
    const int tid = threadIdx.x, lane = tid & 63, w = tid >> 6;
    const int l15 = lane & 15, quad = lane >> 4, e3 = l15 & 7;
    const int wm = w >> 2, wn = w & 3;
    const int mBase = blockIdx.y * 256, nBase = blockIdx.x * 256;

    // staging: thread -> (row sr/sr+64, 16B chunk sc); source col pre-swizzled
    const int sr = tid >> 3, sc = tid & 7;
    const int cs = sc ^ (sr & 7);          // involution; (sr+64)&7 == sr&7
    const int sc8 = sc * 8;
    const short* gA = A + (size_t)(mBase + sr) * 2048 + cs * 8;
    const short* gB = BT + (size_t)(nBase + sr) * 2048 + cs * 8;

    floatx4 acc[8][4];
    #pragma unroll
    for (int mt = 0; mt < 8; ++mt)
        #pragma unroll
        for (int nt = 0; nt < 4; ++nt)
            acc[mt][nt] = (floatx4){0.f, 0.f, 0.f, 0.f};
    short8 bfr[4][2];

    // prologue: tile0 (A+B) fully, B(1); A(1) staged at iter0 p0,p1
    STGBq(0, 0, 0) STGBq(0, 1, 0) STGAq(0, 0, 0) STGAq(0, 1, 0)
    STGBq(1, 0, 1) STGBq(1, 1, 1)
    VMWAIT(4);                     // tile0's 8 loads landed; B(1) in flight
    __builtin_amdgcn_s_barrier();

    for (int it = 0; it < 15; ++it) {
        const int E2 = 2 * it + 2, O1 = 2 * it + 1, O2 = 2 * it + 3;
        PHQ(0, 0, NOP_,      STGAq(1, 0, O1))
        PHQ(0, 1, NOP_,      STGAq(1, 1, O1))
        PHQ(0, 2, NOP_,      STGBq(0, 0, E2))
        PHQ(0, 3, VMWAIT(4), STGBq(0, 1, E2))
        PHQ(1, 0, NOP_,      STGAq(0, 0, E2))
        PHQ(1, 1, NOP_,      STGAq(0, 1, E2))
        PHQ(1, 2, NOP_,      STGBq(1, 0, O2))
        PHQ(1, 3, VMWAIT(4), STGBq(1, 1, O2))
    }
    // tail: tiles 30,31; only A(31) left to stage
    PHQ(0, 0, NOP_,      STGAq(1, 0, 31))
    PHQ(0, 1, NOP_,      STGAq(1, 1, 31))
    PHQ(0, 2, NOP_,      NOP_)
    PHQ(0, 3, VMWAIT(0), NOP_)
    PHQ(1, 0, NOP_,      NOP_)
    PHQ(1, 1, NOP_,      NOP_)
    PHQ(1, 2, NOP_,      NOP_)
    PHQ(1, 3, NOP_,      NOP_)

    // ---- epilogue ----
    const int nb = nBase + wn * 64;
    if (nb < 2560) {
        const float rs = (nb < 2048) ? ASCALE : 1.0f;
        #pragma unroll
        for (int mt = 0; mt < 8; ++mt)
            #pragma unroll
            for (int r = 0; r < 4; ++r) {
                const int m = mBase + wm * 128 + mt * 16 + quad * 4 + r;
                const int t = m & (TT - 1);
                #pragma unroll
                for (int ntp = 0; ntp < 2; ++ntp) {
                    const int i = ntp * 16 + l15;
                    const float c = cosT[t * 32 + i] * rs;
                    const float s = sinT[t * 32 + i] * rs;
                    float x1 = acc[mt][ntp][r], x2 = acc[mt][ntp + 2][r];
                    acc[mt][ntp][r]     = x1 * c - x2 * s;
                    acc[mt][ntp + 2][r] = x2 * c + x1 * s;
                }
            }
    }
    if (nb < 2048) {
        #pragma unroll
        for (int mt = 0; mt < 8; ++mt)
            #pragma unroll
            for (int nt = 0; nt < 4; ++nt) {
                const int n = nb + nt * 16 + l15;
                #pragma unroll
                for (int r = 0; r < 4; ++r) {
                    const int m = mBase + wm * 128 + mt * 16 + quad * 4 + r;
                    q[(size_t)m * 2048 + n] = f2bf(acc[mt][nt][r]);
                }
            }
    } else if (nb < 2560) {
        #pragma unroll
        for (int mt = 0; mt < 8; ++mt)
            #pragma unroll
            for (int nt = 0; nt < 4; ++nt) {
                const int n = nb + nt * 16 + l15 - 2048;
                #pragma unroll
                for (int r = 0; r < 4; ++r) {
                    const int m = mBase + wm * 128 + mt * 16 + quad * 4 + r;
                    kout[(size_t)m * 512 + n] = f2bf(acc[mt][nt][r]);
                }
            }
    } else {
        #pragma unroll
        for (int mt = 0; mt < 8; ++mt)
            #pragma unroll
            for (int nt = 0; nt < 4; ++nt) {
                const int d = nb + nt * 16 + l15 - 2560;
                const int kvh2 = d >> 6, dd = d & 63;
                const int mrow = mBase + wm * 128 + mt * 16 + quad * 4;
                const int bb = mrow >> 11, t0 = mrow & 2047;
                // zero-shuffle-PV permutation: key t0 -> slot (per 32-group)
                const int tl = t0 & 31;
                const int slot = (tl < 16) ? ((tl >> 2) << 3)
                                           : ((((tl - 16) >> 2) << 3) + 4);
                const int t0p = (t0 & ~31) + slot;
                short4v pk;
                #pragma unroll
                for (int r = 0; r < 4; ++r) pk[r] = f2bf(acc[mt][nt][r]);
                *(short4v*)(vout + ((size_t)((bb * 8 + kvh2) * 64 + dd)) * 2048 + t0p) = pk;
            }
    }
}

// ---- gemm_out: 128x256 tile (grid 8x32 = 256 blocks), acc[4][4] -----------
#define LDAo(CC, mt, ks) (*(short8*)&sA[CC][(wm*64 + (mt)*16 + l15)*64 + ((((ks)*4 + quad)^e3)<<3)])
#define LDBo(CC, nt, ks) (*(short8*)&sB[CC][wn>>1][((wn&1)*64 + (nt)*16 + l15)*64 + ((((ks)*4 + quad)^e3)<<3)])

#define STGAo(d, kt) { const short* s_ = gA + (size_t)(kt)*64; \
    gld16(s_,                   &sA[d][sr*64 + sc8]); \
    gld16(s_ + (size_t)64*2048, &sA[d][(sr+64)*64 + sc8]); }
#define STGBo(d, h, kt) { const short* s_ = gB + (size_t)(h)*128*2048 + (size_t)(kt)*64; \
    gld16(s_,                   &sB[d][h][sr*64 + sc8]); \
    gld16(s_ + (size_t)64*2048, &sB[d][h][(sr+64)*64 + sc8]); }

#define PHO(CC, q, VMW, STG) { \
    short8 a0 = LDAo(CC, q, 0), a1 = LDAo(CC, q, 1); \
    if ((q) == 0) { \
        _Pragma("unroll") for (int nt = 0; nt < 4; ++nt) { \
            bfr[nt][0] = LDBo(CC, nt, 0); bfr[nt][1] = LDBo(CC, nt, 1); } } \
    STG; \
    __builtin_amdgcn_s_barrier(); \
    LGKM0; \
    __builtin_amdgcn_sched_barrier(0); \
    __builtin_amdgcn_s_setprio(1); \
    _Pragma("unroll") for (int nt = 0; nt < 4; ++nt) { \
        acc[q][nt] = __builtin_amdgcn_mfma_f32_16x16x32_bf16(a0, bfr[nt][0], acc[q][nt], 0, 0, 0); \
        acc[q][nt] = __builtin_amdgcn_mfma_f32_16x16x32_bf16(a1, bfr[nt][1], acc[q][nt], 0, 0, 0); } \
    __builtin_amdgcn_s_setprio(0); \
    VMW; \
    __builtin_amdgcn_s_barrier(); \
}

__global__ __launch_bounds__(512) void gemm_out(
    const short* __restrict__ A, const short* __restrict__ BT,
    const float* __restrict__ bias, float* __restrict__ out)
{
    __shared__ short sA[2][128 * 64];      // 32 KB  [dbuf][row*64+col]
    __shared__ short sB[2][2][128 * 64];   // 64 KB
    const int tid = threadIdx.x, lane = tid & 63, w = tid >> 6;
    const int l15 = lane & 15, quad = lane >> 4, e3 = l15 & 7;
    const int wm = w >> 2, wn = w & 3;
    const int mBase = blockIdx.y * 128, nBase = blockIdx.x * 256;

    const int sr = tid >> 3, sc = tid & 7;
    const int cs = sc ^ (sr & 7);
    const int sc8 = sc * 8;
    const short* gA = A + (size_t)(mBase + sr) * 2048 + cs * 8;
    const short* gB = BT + (size_t)(nBase + sr) * 2048 + cs * 8;

    floatx4 acc[4][4];
    #pragma unroll
    for (int mt = 0; mt < 4; ++mt)
        #pragma unroll
        for (int nt = 0; nt < 4; ++nt)
            acc[mt][nt] = (floatx4){0.f, 0.f, 0.f, 0.f};
    short8 bfr[4][2];

    // prologue: B(0), A(0), B(1); A(1) staged at iter0 p0
    STGBo(0, 0, 0) STGBo(0, 1, 0) STGAo(0, 0)
    STGBo(1, 0, 1) STGBo(1, 1, 1)
    VMWAIT(4);
    __builtin_amdgcn_s_barrier();

    for (int it = 0; it < 15; ++it) {
        const int E2 = 2 * it + 2, O1 = 2 * it + 1, O2 = 2 * it + 3;
        PHO(0, 0, NOP_,      STGAo(1, O1))
        PHO(0, 1, NOP_,      STGBo(0, 0, E2))
        PHO(0, 2, NOP_,      STGBo(0, 1, E2))
        PHO(0, 3, VMWAIT(4), NOP_)
        PHO(1, 0, NOP_,      STGAo(0, E2))
        PHO(1, 1, NOP_,      STGBo(1, 0, O2))
        PHO(1, 2, NOP_,      STGBo(1, 1, O2))
        PHO(1, 3, VMWAIT(4), NOP_)
    }
    PHO(0, 0, NOP_,      STGAo(1, 31))
    PHO(0, 1, NOP_,      NOP_)
    PHO(0, 2, NOP_,      NOP_)
    PHO(0, 3, VMWAIT(0), NOP_)
    PHO(1, 0, NOP_,      NOP_)
    PHO(1, 1, NOP_,      NOP_)
    PHO(1, 2, NOP_,      NOP_)
    PHO(1, 3, NOP_,      NOP_)

    #pragma unroll
    for (int mt = 0; mt < 4; ++mt)
        #pragma unroll
        for (int nt = 0; nt < 4; ++nt) {
            const int n = nBase + wn * 64 + nt * 16 + l15;
            const float bv = bias[n];
            #pragma unroll
            for (int r = 0; r < 4; ++r) {
                const int m = mBase + wm * 64 + mt * 16 + quad * 4 + r;
                out[(size_t)m * 2048 + n] = acc[mt][nt][r] + bv;
            }
        }
}

// ---------------------------------------------------------------------------
// Causal GQA flash attention v5b (= R8-verified structure, one change):
//  * GQA-shared K/V, swapped QK^T, XOR swizzle, zero-shuffle PV with
//    key-permuted V, K/V double-buffer + 1 barrier/tile  (all R8-proven)
//  * __expf replaces OCML exp2f: HIP-documented native intrinsic
//    (v_mul + v_exp_f32, compiler-managed hazards). Scores pre-scaled by
//    1/8 in NATURAL domain (ASCALE=0.125). -inf -> 0 preserved.
//  * l-sum kept as R8's shfl path (lacc-MFMA deferred for isolation).
// ---------------------------------------------------------------------------
#define LDH 64

__global__ __launch_bounds__(512, 4) void attn_mfma(
    const short* __restrict__ q, const short* __restrict__ k,
    const short* __restrict__ vT, short* __restrict__ ctx)
{
    __shared__ short Ks[2][64 * LDH];         // 16 KB  [db][key][d]  swizzled
    __shared__ short Vt[2][64 * LDH];         // 16 KB  [db][d][slot] swizzled

    const int b = blockIdx.z;
    const int qt = b ? blockIdx.x : 31 - blockIdx.x;   // pair heavy with light
    const int kvh = blockIdx.y;
    const int tid = threadIdx.x;
    const int lane = tid & 63, wave = tid >> 6;
    const int l15 = lane & 15, quad = lane >> 4;
    const int e3 = l15 & 7;
    const int h = kvh * 4 + (wave >> 1);
    const int whalf = wave & 1;

    const int srow = tid >> 3, schunk = tid & 7;
    const int soff = srow * LDH + ((schunk ^ (srow & 7)) << 3);
    const short* gK = k + ((size_t)(b * TT + srow)) * 512 + kvh * 64 + schunk * 8;
    const short* gV = vT + ((size_t)((b * 8 + kvh) * 64 + srow)) * 2048 + schunk * 8;

    // tile 0 loads (hide under Q load)
    short8 rK = *(const short8*)gK;
    short8 rV = *(const short8*)gV;

    // Q fragments direct to registers (pre-scaled by ASCALE)
    short8 qf[2][2];
    {
        const size_t qrow = (size_t)(b * TT + qt * 64 + whalf * 32);
        #pragma unroll
        for (int tq = 0; tq < 2; ++tq)
            #pragma unroll
            for (int kk = 0; kk < 2; ++kk)
                qf[tq][kk] = *(const short8*)(q + (qrow + tq * 16 + l15) * 2048
                                              + h * 64 + kk * 32 + quad * 8);
    }

    floatx4 oacc[2][4];
    #pragma unroll
    for (int tq = 0; tq < 2; ++tq)
        #pragma unroll
        for (int db = 0; db < 4; ++db)
            oacc[tq][db] = (floatx4){0.f, 0.f, 0.f, 0.f};
    float l_part[2] = {0.f, 0.f};

    const int c0 = (quad ^ e3) << 3;
    const int c1 = ((4 + quad) ^ e3) << 3;

    // prologue: stage tile 0 into buf 0; issue tile 1 loads
    *(short8*)&Ks[0][soff] = rK;
    *(short8*)&Vt[0][soff] = rV;
    if (qt > 0) {
        gK += (size_t)64 * 512;
        gV += 64;
        rK = *(const short8*)gK;
        rV = *(const short8*)gV;
    }
    __syncthreads();

    for (int kt = 0; kt <= qt; ++kt) {
        const int cb = kt & 1;
        if (kt < qt) {                        // stage tile kt+1 into other buf
            *(short8*)&Ks[cb ^ 1][soff] = rK; // vmcnt wait is 1 tile old
            *(short8*)&Vt[cb ^ 1][soff] = rV;
            if (kt + 1 < qt) {                // issue tile kt+2 loads
                gK += (size_t)64 * 512;
                gV += 64;
                rK = *(const short8*)gK;
                rV = *(const short8*)gV;
            }
        }

        // ---- S^T strip = K(64xd) . Q^T : lane holds k = tk*16+quad*4+r, q = l15
        floatx4 sacc[4][2];
        #pragma unroll
        for (int tk = 0; tk < 4; ++tk)
            #pragma unroll
            for (int tq = 0; tq < 2; ++tq)
                sacc[tk][tq] = (floatx4){0.f, 0.f, 0.f, 0.f};
        __builtin_amdgcn_s_setprio(1);
        #pragma unroll
        for (int tk = 0; tk < 4; ++tk) {
            short8 kf0 = *(short8*)&Ks[cb][(tk * 16 + l15) * LDH + c0];
            short8 kf1 = *(short8*)&Ks[cb][(tk * 16 + l15) * LDH + c1];
            #pragma unroll
            for (int tq = 0; tq < 2; ++tq) {
                sacc[tk][tq] = __builtin_amdgcn_mfma_f32_16x16x32_bf16(kf0, qf[tq][0], sacc[tk][tq], 0, 0, 0);
                sacc[tk][tq] = __builtin_amdgcn_mfma_f32_16x16x32_bf16(kf1, qf[tq][1], sacc[tk][tq], 0, 0, 0);
            }
        }
        __builtin_amdgcn_s_setprio(0);

        if (kt == qt) {
            #pragma unroll
            for (int tk = 0; tk < 4; ++tk)
                #pragma unroll
                for (int tq = 0; tq < 2; ++tq) {
                    const int qloc = whalf * 32 + tq * 16 + l15;
                    #pragma unroll
                    for (int r = 0; r < 4; ++r)
                        if (tk * 16 + quad * 4 + r > qloc) sacc[tk][tq][r] = -INFINITY;
                }
        }

        // ---- P = exp(S') via native __expf; accumulate l per-lane
        #pragma unroll
        for (int tk = 0; tk < 4; ++tk)
            #pragma unroll
            for (int tq = 0; tq < 2; ++tq) {
                float p0 = __expf(sacc[tk][tq][0]);
                float p1 = __expf(sacc[tk][tq][1]);
                float p2 = __expf(sacc[tk][tq][2]);
                float p3 = __expf(sacc[tk][tq][3]);
                l_part[tq] += (p0 + p1) + (p2 + p3);
                sacc[tk][tq][0] = p0; sacc[tk][tq][1] = p1;
                sacc[tk][tq][2] = p2; sacc[tk][tq][3] = p3;
            }
        short8 pf[2][2];
        #pragma unroll
        for (int tq = 0; tq < 2; ++tq)
            #pragma unroll
            for (int g = 0; g < 2; ++g) {
                union { short8 s; unsigned u[4]; } uf;
                uf.u[0] = cvtpk(sacc[2 * g][tq][0],     sacc[2 * g][tq][1]);
                uf.u[1] = cvtpk(sacc[2 * g][tq][2],     sacc[2 * g][tq][3]);
                uf.u[2] = cvtpk(sacc[2 * g + 1][tq][0], sacc[2 * g + 1][tq][1]);
                uf.u[3] = cvtpk(sacc[2 * g + 1][tq][2], sacc[2 * g + 1][tq][3]);
                pf[tq][g] = uf.s;
            }

        // ---- O += P . V   (A = lane-local P frags, B = permuted V^T rows)
        __builtin_amdgcn_s_setprio(1);
        #pragma unroll
        for (int db = 0; db < 4; ++db) {
            short8 vf0 = *(short8*)&Vt[cb][(db * 16 + l15) * LDH + c0];
            short8 vf1 = *(short8*)&Vt[cb][(db * 16 + l15) * LDH + c1];
            #pragma unroll
            for (int tq = 0; tq < 2; ++tq) {
                oacc[tq][db] = __builtin_amdgcn_mfma_f32_16x16x32_bf16(pf[tq][0], vf0, oacc[tq][db], 0, 0, 0);
                oacc[tq][db] = __builtin_amdgcn_mfma_f32_16x16x32_bf16(pf[tq][1], vf1, oacc[tq][db], 0, 0, 0);
            }
        }
        __builtin_amdgcn_s_setprio(0);

        __syncthreads();                      // single barrier per K-tile
    }

    #pragma unroll
    for (int off = 16; off < 64; off <<= 1) {
        l_part[0] += __shfl_xor(l_part[0], off, 64);
        l_part[1] += __shfl_xor(l_part[1], off, 64);
    }

    #pragma unroll
    for (int tq = 0; tq < 2; ++tq)
        #pragma unroll
        for (int r = 0; r < 4; ++r) {
            const float denom = __shfl(l_part[tq], quad * 4 + r, 64);
            const float inv = 1.0f / denom;
            const int row = qt * 64 + whalf * 32 + tq * 16 + quad * 4 + r;
            #pragma unroll
            for (int db = 0; db < 4; ++db)
                ctx[((size_t)(b * TT + row) * 32 + h) * 64 + db * 16 + l15] =
                    f2bf(oacc[tq][db][r] * inv);
        }
}

extern "C" void kernel_launch(void* const* d_in, const int* in_sizes, int n_in,
                              void* d_out, int out_size, void* d_ws, size_t ws_size,
                              hipStream_t stream) {
    const float* x    = (const float*)d_in[0];
    const float* Wq   = (const float*)d_in[1];
    const float* Wk   = (const float*)d_in[2];
    const float* Wv   = (const float*)d_in[3];
    const float* Wo   = (const float*)d_in[4];
    const float* bout = (const float*)d_in[5];
    float* out = (float*)d_out;

    // workspace (shorts): xb | WqkvT | WoT | qb | kb | vb(T) | ctx | tables
    short* xb    = (short*)d_ws;
    short* WqkvT = xb + (size_t)8388608;
    short* WoT   = WqkvT + (size_t)6291456;
    short* qb    = WoT + (size_t)4194304;
    short* kb    = qb + (size_t)8388608;
    short* vb    = kb + (size_t)2097152;
    short* ctx   = vb + (size_t)2097152;
    float* cosT  = (float*)(ctx + (size_t)8388608);
    float* sinT  = cosT + 65536;

    rope_tables<<<256, 256, 0, stream>>>(cosT, sinT);
    convert_bf16<<<4096, 256, 0, stream>>>(x, xb, 8388608);
    transpose_conv<<<dim3(64, 64), 256, 0, stream>>>(Wq, WqkvT, 2048, 2048);
    transpose_conv<<<dim3(16, 64), 256, 0, stream>>>(Wk, WqkvT + (size_t)2048 * 2048, 2048, 512);
    transpose_conv<<<dim3(16, 64), 256, 0, stream>>>(Wv, WqkvT + (size_t)2560 * 2048, 2048, 512);
    transpose_conv<<<dim3(64, 64), 256, 0, stream>>>(Wo, WoT, 2048, 2048);

    gemm_qkv<<<dim3(12, 16), 512, 0, stream>>>(xb, WqkvT, cosT, sinT, qb, kb, vb);

    attn_mfma<<<dim3(32, 8, 2), 512, 0, stream>>>(qb, kb, vb, ctx);

    gemm_out<<<dim3(8, 32), 512, 0, stream>>>(ctx, WoT, bout, out);
}

// Round 12
// 268.371 us; speedup vs baseline: 1.1163x; 1.0439x over previous
//
#include <hip/hip_runtime.h>
#include <math.h>

#define BB 2
#define TT 2048
#define NH 32
#define NKV 8
#define NROWS 4096

typedef __attribute__((ext_vector_type(4))) float floatx4;
typedef __attribute__((ext_vector_type(8))) short short8;
typedef __attribute__((ext_vector_type(4))) short short4v;
typedef __attribute__((ext_vector_type(2))) unsigned int uint2v;

__device__ __forceinline__ short f2bf(float f) {
    union { float fv; unsigned u; } v; v.fv = f;
    unsigned r = v.u + 0x7FFFu + ((v.u >> 16) & 1u);   // RNE
    return (short)(r >> 16);
}
__device__ __forceinline__ float bf2f(short s) {
    union { float fv; unsigned u; } v;
    v.u = ((unsigned)(unsigned short)s) << 16;
    return v.fv;
}
// packed f32x2 -> bf16x2 (RNE), single VALU op (T12 primitive, gfx950)
__device__ __forceinline__ unsigned cvtpk(float lo, float hi) {
    unsigned r;
    asm("v_cvt_pk_bf16_f32 %0, %1, %2" : "=v"(r) : "v"(lo), "v"(hi));
    return r;
}
__device__ __forceinline__ void gld16(const short* g, short* l) {
    __builtin_amdgcn_global_load_lds((const __attribute__((address_space(1))) void*)g,
                                     (__attribute__((address_space(3))) void*)l, 16, 0, 0);
}

#define STR2_(x) #x
#define STR_(x) STR2_(x)
#define VMWAIT(n) asm volatile("s_waitcnt vmcnt(" STR_(n) ")" ::: "memory")
#define LGKM0 asm volatile("s_waitcnt lgkmcnt(0)" ::: "memory")

// ---------------------------------------------------------------------------
// Fused prep: rope tables + x->bf16 + 4 weight transpose-converts in ONE
// launch (blockIdx-range dispatch; saves 5 launch gaps, overlaps tails).
//   [0,256)        rope_tables           (256 thr: idx = bid*256+tid)
//   [256,4352)     convert_bf16 x        (4096 blocks)
//   [4352,8448)    transpose Wq  (64x64)
//   [8448,9472)    transpose Wk  (16x64)
//   [9472,10496)   transpose Wv  (16x64)
//   [10496,14592)  transpose Wo  (64x64)
// Inner code mechanically identical to the R10-verified standalone kernels.
// ---------------------------------------------------------------------------
__global__ __launch_bounds__(256) void prep(
    const float* __restrict__ x,
    const float* __restrict__ Wq, const float* __restrict__ Wk,
    const float* __restrict__ Wv, const float* __restrict__ Wo,
    short* __restrict__ xb, short* __restrict__ WqkvT, short* __restrict__ WoT,
    float* __restrict__ cosT, float* __restrict__ sinT)
{
    __shared__ short T[32][34];
    const int bid = blockIdx.x;
    if (bid < 256) {
        int idx = bid * 256 + threadIdx.x;                 // 65536
        int t = idx >> 5, i = idx & 31;
        float ang = (float)t * expf(-0.28782313662f * (float)i);  // 10000^(-i/32)
        float s, c;
        sincosf(ang, &s, &c);
        cosT[idx] = c;
        sinT[idx] = s;
    } else if (bid < 4352) {
        int idx = ((bid - 256) * 256 + threadIdx.x) * 8;   // 8388608 elems
        float4 a = *(const float4*)(x + idx);
        float4 b = *(const float4*)(x + idx + 4);
        short8 o;
        o[0] = f2bf(a.x); o[1] = f2bf(a.y); o[2] = f2bf(a.z); o[3] = f2bf(a.w);
        o[4] = f2bf(b.x); o[5] = f2bf(b.y); o[6] = f2bf(b.z); o[7] = f2bf(b.w);
        *(short8*)(xb + idx) = o;
    } else {
        const float* src; short* dst; int N, bx, by;
        if (bid < 8448) {
            int i = bid - 4352;  src = Wq; dst = WqkvT;                        N = 2048; bx = i & 63; by = i >> 6;
        } else if (bid < 9472) {
            int i = bid - 8448;  src = Wk; dst = WqkvT + (size_t)2048 * 2048;  N = 512;  bx = i & 15; by = i >> 4;
        } else if (bid < 10496) {
            int i = bid - 9472;  src = Wv; dst = WqkvT + (size_t)2560 * 2048;  N = 512;  bx = i & 15; by = i >> 4;
        } else {
            int i = bid - 10496; src = Wo; dst = WoT;                          N = 2048; bx = i & 63; by = i >> 6;
        }
        const int tx = threadIdx.x & 31, ty = threadIdx.x >> 5;
        const int i0 = by * 32, j0 = bx * 32;
        #pragma unroll
        for (int i = 0; i < 4; ++i)
            T[ty + 8 * i][tx] = f2bf(src[(size_t)(i0 + ty + 8 * i) * N + j0 + tx]);
        __syncthreads();
        #pragma unroll
        for (int i = 0; i < 4; ++i)
            dst[(size_t)(j0 + ty + 8 * i) * 2048 + i0 + tx] = T[tx][ty + 8 * i];
    }
}

// ===========================================================================
// 8-phase GEMM (m201 template ported, verified R6): BK=64 per K-tile,
// 2 K-tiles per iteration, 8 phases/iter; counted vmcnt never drains
// in-loop; T2 read-swizzle via pre-swizzled source column (rule 21).
// ===========================================================================

// softmax scale folded into Q, NATURAL-exp domain: 1/sqrt(d) = 1/8 exactly.
// attention uses __expf (native v_exp path, compiler-managed hazards).
#define ASCALE 0.125f

// ---- qkv: 256x256 tile, acc[8][4], A split in 2 halves --------------------
#define LDAq(CC, mt, ks) (*(short8*)&sA[CC][wm][((mt)*16 + l15)*64 + ((((ks)*4 + quad)^e3)<<3)])
#define LDBq(CC, nt, ks) (*(short8*)&sB[CC][wn>>1][((wn&1)*64 + (nt)*16 + l15)*64 + ((((ks)*4 + quad)^e3)<<3)])

#define STGAq(d, h, kt) { const short* s_ = gA + (size_t)(h)*128*2048 + (size_t)(kt)*64; \
    gld16(s_,                   &sA[d][h][sr*64 + sc8]); \
    gld16(s_ + (size_t)64*2048, &sA[d][h][(sr+64)*64 + sc8]); }
#define STGBq(d, h, kt) { const short* s_ = gB + (size_t)(h)*128*2048 + (size_t)(kt)*64; \
    gld16(s_,                   &sB[d][h][sr*64 + sc8]); \
    gld16(s_ + (size_t)64*2048, &sB[d][h][(sr+64)*64 + sc8]); }

#define PHQ(CC, q, VMW, STG) { \
    short8 a00 = LDAq(CC, 2*(q), 0),   a01 = LDAq(CC, 2*(q), 1); \
    short8 a10 = LDAq(CC, 2*(q)+1, 0), a11 = LDAq(CC, 2*(q)+1, 1); \
    if ((q) == 0) { \
        _Pragma("unroll") for (int nt = 0; nt < 4; ++nt) { \
            bfr[nt][0] = LDBq(CC, nt, 0); bfr[nt][1] = LDBq(CC, nt, 1); } } \
    STG; \
    __builtin_amdgcn_s_barrier(); \
    LGKM0; \
    __builtin_amdgcn_sched_barrier(0); \
    __builtin_amdgcn_s_setprio(1); \
    _Pragma("unroll") for (int nt = 0; nt < 4; ++nt) { \
        acc[2*(q)][nt]   = __builtin_amdgcn_mfma_f32_16x16x32_bf16(a00, bfr[nt][0], acc[2*(q)][nt], 0, 0, 0); \
        acc[2*(q)][nt]   = __builtin_amdgcn_mfma_f32_16x16x32_bf16(a01, bfr[nt][1], acc[2*(q)][nt], 0, 0, 0); \
        acc[2*(q)+1][nt] = __builtin_amdgcn_mfma_f32_16x16x32_bf16(a10, bfr[nt][0], acc[2*(q)+1][nt], 0, 0, 0); \
        acc[2*(q)+1][nt] = __builtin_amdgcn_mfma_f32_16x16x32_bf16(a11, bfr[nt][1], acc[2*(q)+1][nt], 0, 0, 0); } \
    __builtin_amdgcn_s_setprio(0); \
    VMW; \
    __builtin_amdgcn_s_barrier(); \
}

#define NOP_ ((void)0)

// QKV GEMM with fused RoPE. q pre-scaled by ASCALE; v written transposed AND
// key-permuted per 32-key group (zero-shuffle PV: slot 8a+j <- key 4a+j for
// j<4, key 16+4a+(j-4) for j>=4) so attention's PV A-fragments are lane-local.
__global__ __launch_bounds__(512) void gemm_qkv(
    const short* __restrict__ A, const short* __restrict__ BT,
    const float* __restrict__ cosT, const float* __restrict__ sinT,
    short* __restrict__ q, short* __restrict__ kout, short* __restrict__ vout)
{
    __shared__ short sA[2][2][128 * 64];   // 64 KB  [dbuf][half][row*64+col]
    __shared__ short sB[2][2][128 * 64];   // 64 KB
    const int tid = threadIdx.x, lane = tid & 63, w = tid >> 6;
    const int l15 = lane & 15, quad = lane >> 4, e3 = l15 & 7;
    const int wm = w >> 2, wn = w & 3;
    const int mBase = blockIdx.y * 256, nBase = blockIdx.x * 256;

    // staging: thread -> (row sr/sr+64, 16B chunk sc); source col pre-swizzled
    const int sr = tid >> 3, sc = tid & 7;
    const int cs = sc ^ (sr & 7);          // involution; (sr+64)&7 == sr&7
    const int sc8 = sc * 8;
    const short* gA = A + (size_t)(mBase + sr) * 2048 + cs * 8;
    const short* gB = BT + (size_t)(nBase + sr) * 2048 + cs * 8;

    floatx4 acc[8][4];
    #pragma unroll
    for (int mt = 0; mt < 8; ++mt)
        #pragma unroll
        for (int nt = 0; nt < 4; ++nt)
            acc[mt][nt] = (floatx4){0.f, 0.f, 0.f, 0.f};
    short8 bfr[4][2];

    // prologue: tile0 (A+B) fully, B(1); A(1) staged at iter0 p0,p1
    STGBq(0, 0, 0) STGBq(0, 1, 0) STGAq(0, 0, 0) STGAq(0, 1, 0)
    STGBq(1, 0, 1) STGBq(1, 1, 1)
    VMWAIT(4);                     // tile0's 8 loads landed; B(1) in flight
    __builtin_amdgcn_s_barrier();

    for (int it = 0; it < 15; ++it) {
        const int E2 = 2 * it + 2, O1 = 2 * it + 1, O2 = 2 * it + 3;
        PHQ(0, 0, NOP_,      STGAq(1, 0, O1))
        PHQ(0, 1, NOP_,      STGAq(1, 1, O1))
        PHQ(0, 2, NOP_,      STGBq(0, 0, E2))
        PHQ(0, 3, VMWAIT(4), STGBq(0, 1, E2))
        PHQ(1, 0, NOP_,      STGAq(0, 0, E2))
        PHQ(1, 1, NOP_,      STGAq(0, 1, E2))
        PHQ(1, 2, NOP_,      STGBq(1, 0, O2))
        PHQ(1, 3, VMWAIT(4), STGBq(1, 1, O2))
    }
    // tail: tiles 30,31; only A(31) left to stage
    PHQ(0, 0, NOP_,      STGAq(1, 0, 31))
    PHQ(0, 1, NOP_,      STGAq(1, 1, 31))
    PHQ(0, 2, NOP_,      NOP_)
    PHQ(0, 3, VMWAIT(0), NOP_)
    PHQ(1, 0, NOP_,      NOP_)
    PHQ(1, 1, NOP_,      NOP_)
    PHQ(1, 2, NOP_,      NOP_)
    PHQ(1, 3, NOP_,      NOP_)

    // ---- epilogue ----
    const int nb = nBase + wn * 64;
    if (nb < 2560) {
        const float rs = (nb < 2048) ? ASCALE : 1.0f;
        #pragma unroll
        for (int mt = 0; mt < 8; ++mt)
            #pragma unroll
            for (int r = 0; r < 4; ++r) {
                const int m = mBase + wm * 128 + mt * 16 + quad * 4 + r;
                const int t = m & (TT - 1);
                #pragma unroll
                for (int ntp = 0; ntp < 2; ++ntp) {
                    const int i = ntp * 16 + l15;
                    const float c = cosT[t * 32 + i] * rs;
                    const float s = sinT[t * 32 + i] * rs;
                    float x1 = acc[mt][ntp][r], x2 = acc[mt][ntp + 2][r];
                    acc[mt][ntp][r]     = x1 * c - x2 * s;
                    acc[mt][ntp + 2][r] = x2 * c + x1 * s;
                }
            }
    }
    if (nb < 2048) {
        #pragma unroll
        for (int mt = 0; mt < 8; ++mt)
            #pragma unroll
            for (int nt = 0; nt < 4; ++nt) {
                const int n = nb + nt * 16 + l15;
                #pragma unroll
                for (int r = 0; r < 4; ++r) {
                    const int m = mBase + wm * 128 + mt * 16 + quad * 4 + r;
                    q[(size_t)m * 2048 + n] = f2bf(acc[mt][nt][r]);
                }
            }
    } else if (nb < 2560) {
        #pragma unroll
        for (int mt = 0; mt < 8; ++mt)
            #pragma unroll
            for (int nt = 0; nt < 4; ++nt) {
                const int n = nb + nt * 16 + l15 - 2048;
                #pragma unroll
                for (int r = 0; r < 4; ++r) {
                    const int m = mBase + wm * 128 + mt * 16 + quad * 4 + r;
                    kout[(size_t)m * 512 + n] = f2bf(acc[mt][nt][r]);
                }
            }
    } else {
        #pragma unroll
        for (int mt = 0; mt < 8; ++mt)
            #pragma unroll
            for (int nt = 0; nt < 4; ++nt) {
                const int d = nb + nt * 16 + l15 - 2560;
                const int kvh2 = d >> 6, dd = d & 63;
                const int mrow = mBase + wm * 128 + mt * 16 + quad * 4;
                const int bb = mrow >> 11, t0 = mrow & 2047;
                // zero-shuffle-PV permutation: key t0 -> slot (per 32-group)
                const int tl = t0 & 31;
                const int slot = (tl < 16) ? ((tl >> 2) << 3)
                                           : ((((tl - 16) >> 2) << 3) + 4);
                const int t0p = (t0 & ~31) + slot;
                short4v pk;
                #pragma unroll
                for (int r = 0; r < 4; ++r) pk[r] = f2bf(acc[mt][nt][r]);
                *(short4v*)(vout + ((size_t)((bb * 8 + kvh2) * 64 + dd)) * 2048 + t0p) = pk;
            }
    }
}

// ---- gemm_out: 128x256 tile (grid 8x32 = 256 blocks), acc[4][4] -----------
#define LDAo(CC, mt, ks) (*(short8*)&sA[CC][(wm*64 + (mt)*16 + l15)*64 + ((((ks)*4 + quad)^e3)<<3)])
#define LDBo(CC, nt, ks) (*(short8*)&sB[CC][wn>>1][((wn&1)*64 + (nt)*16 + l15)*64 + ((((ks)*4 + quad)^e3)<<3)])

#define STGAo(d, kt) { const short* s_ = gA + (size_t)(kt)*64; \
    gld16(s_,                   &sA[d][sr*64 + sc8]); \
    gld16(s_ + (size_t)64*2048, &sA[d][(sr+64)*64 + sc8]); }
#define STGBo(d, h, kt) { const short* s_ = gB + (size_t)(h)*128*2048 + (size_t)(kt)*64; \
    gld16(s_,                   &sB[d][h][sr*64 + sc8]); \
    gld16(s_ + (size_t)64*2048, &sB[d][h][(sr+64)*64 + sc8]); }

#define PHO(CC, q, VMW, STG) { \
    short8 a0 = LDAo(CC, q, 0), a1 = LDAo(CC, q, 1); \
    if ((q) == 0) { \
        _Pragma("unroll") for (int nt = 0; nt < 4; ++nt) { \
            bfr[nt][0] = LDBo(CC, nt, 0); bfr[nt][1] = LDBo(CC, nt, 1); } } \
    STG; \
    __builtin_amdgcn_s_barrier(); \
    LGKM0; \
    __builtin_amdgcn_sched_barrier(0); \
    __builtin_amdgcn_s_setprio(1); \
    _Pragma("unroll") for (int nt = 0; nt < 4; ++nt) { \
        acc[q][nt] = __builtin_amdgcn_mfma_f32_16x16x32_bf16(a0, bfr[nt][0], acc[q][nt], 0, 0, 0); \
        acc[q][nt] = __builtin_amdgcn_mfma_f32_16x16x32_bf16(a1, bfr[nt][1], acc[q][nt], 0, 0, 0); } \
    __builtin_amdgcn_s_setprio(0); \
    VMW; \
    __builtin_amdgcn_s_barrier(); \
}

__global__ __launch_bounds__(512) void gemm_out(
    const short* __restrict__ A, const short* __restrict__ BT,
    const float* __restrict__ bias, float* __restrict__ out)
{
    __shared__ short sA[2][128 * 64];      // 32 KB  [dbuf][row*64+col]
    __shared__ short sB[2][2][128 * 64];   // 64 KB
    const int tid = threadIdx.x, lane = tid & 63, w = tid >> 6;
    const int l15 = lane & 15, quad = lane >> 4, e3 = l15 & 7;
    const int wm = w >> 2, wn = w & 3;
    const int mBase = blockIdx.y * 128, nBase = blockIdx.x * 256;

    const int sr = tid >> 3, sc = tid & 7;
    const int cs = sc ^ (sr & 7);
    const int sc8 = sc * 8;
    const short* gA = A + (size_t)(mBase + sr) * 2048 + cs * 8;
    const short* gB = BT + (size_t)(nBase + sr) * 2048 + cs * 8;

    floatx4 acc[4][4];
    #pragma unroll
    for (int mt = 0; mt < 4; ++mt)
        #pragma unroll
        for (int nt = 0; nt < 4; ++nt)
            acc[mt][nt] = (floatx4){0.f, 0.f, 0.f, 0.f};
    short8 bfr[4][2];

    // prologue: B(0), A(0), B(1); A(1) staged at iter0 p0
    STGBo(0, 0, 0) STGBo(0, 1, 0) STGAo(0, 0)
    STGBo(1, 0, 1) STGBo(1, 1, 1)
    VMWAIT(4);
    __builtin_amdgcn_s_barrier();

    for (int it = 0; it < 15; ++it) {
        const int E2 = 2 * it + 2, O1 = 2 * it + 1, O2 = 2 * it + 3;
        PHO(0, 0, NOP_,      STGAo(1, O1))
        PHO(0, 1, NOP_,      STGBo(0, 0, E2))
        PHO(0, 2, NOP_,      STGBo(0, 1, E2))
        PHO(0, 3, VMWAIT(4), NOP_)
        PHO(1, 0, NOP_,      STGAo(0, E2))
        PHO(1, 1, NOP_,      STGBo(1, 0, O2))
        PHO(1, 2, NOP_,      STGBo(1, 1, O2))
        PHO(1, 3, VMWAIT(4), NOP_)
    }
    PHO(0, 0, NOP_,      STGAo(1, 31))
    PHO(0, 1, NOP_,      NOP_)
    PHO(0, 2, NOP_,      NOP_)
    PHO(0, 3, VMWAIT(0), NOP_)
    PHO(1, 0, NOP_,      NOP_)
    PHO(1, 1, NOP_,      NOP_)
    PHO(1, 2, NOP_,      NOP_)
    PHO(1, 3, NOP_,      NOP_)

    #pragma unroll
    for (int mt = 0; mt < 4; ++mt)
        #pragma unroll
        for (int nt = 0; nt < 4; ++nt) {
            const int n = nBase + wn * 64 + nt * 16 + l15;
            const float bv = bias[n];
            #pragma unroll
            for (int r = 0; r < 4; ++r) {
                const int m = mBase + wm * 64 + mt * 16 + quad * 4 + r;
                out[(size_t)m * 2048 + n] = acc[mt][nt][r] + bv;
            }
        }
}

// ---------------------------------------------------------------------------
// Causal GQA flash attention v5b (R10-VERIFIED, byte-identical):
//  * GQA-shared K/V, swapped QK^T, XOR swizzle, zero-shuffle PV with
//    key-permuted V, K/V double-buffer + 1 barrier/tile, __expf.
//  * l-sum via per-lane adds + shfl (the adds between __expf and cvtpk are
//    ALSO the hazard guard — removing them correlated with NaN in R9/R11;
//    lacc-MFMA line abandoned).
// ---------------------------------------------------------------------------
#define LDH 64

__global__ __launch_bounds__(512, 4) void attn_mfma(
    const short* __restrict__ q, const short* __restrict__ k,
    const short* __restrict__ vT, short* __restrict__ ctx)
{
    __shared__ short Ks[2][64 * LDH];         // 16 KB  [db][key][d]  swizzled
    __shared__ short Vt[2][64 * LDH];         // 16 KB  [db][d][slot] swizzled

    const int b = blockIdx.z;
    const int qt = b ? blockIdx.x : 31 - blockIdx.x;   // pair heavy with light
    const int kvh = blockIdx.y;
    const int tid = threadIdx.x;
    const int lane = tid & 63, wave = tid >> 6;
    const int l15 = lane & 15, quad = lane >> 4;
    const int e3 = l15 & 7;
    const int h = kvh * 4 + (wave >> 1);
    const int whalf = wave & 1;

    const int srow = tid >> 3, schunk = tid & 7;
    const int soff = srow * LDH + ((schunk ^ (srow & 7)) << 3);
    const short* gK = k + ((size_t)(b * TT + srow)) * 512 + kvh * 64 + schunk * 8;
    const short* gV = vT + ((size_t)((b * 8 + kvh) * 64 + srow)) * 2048 + schunk * 8;

    // tile 0 loads (hide under Q load)
    short8 rK = *(const short8*)gK;
    short8 rV = *(const short8*)gV;

    // Q fragments direct to registers (pre-scaled by ASCALE)
    short8 qf[2][2];
    {
        const size_t qrow = (size_t)(b * TT + qt * 64 + whalf * 32);
        #pragma unroll
        for (int tq = 0; tq < 2; ++tq)
            #pragma unroll
            for (int kk = 0; kk < 2; ++kk)
                qf[tq][kk] = *(const short8*)(q + (qrow + tq * 16 + l15) * 2048
                                              + h * 64 + kk * 32 + quad * 8);
    }

    floatx4 oacc[2][4];
    #pragma unroll
    for (int tq = 0; tq < 2; ++tq)
        #pragma unroll
        for (int db = 0; db < 4; ++db)
            oacc[tq][db] = (floatx4){0.f, 0.f, 0.f, 0.f};
    float l_part[2] = {0.f, 0.f};

    const int c0 = (quad ^ e3) << 3;
    const int c1 = ((4 + quad) ^ e3) << 3;

    // prologue: stage tile 0 into buf 0; issue tile 1 loads
    *(short8*)&Ks[0][soff] = rK;
    *(short8*)&Vt[0][soff] = rV;
    if (qt > 0) {
        gK += (size_t)64 * 512;
        gV += 64;
        rK = *(const short8*)gK;
        rV = *(const short8*)gV;
    }
    __syncthreads();

    for (int kt = 0; kt <= qt; ++kt) {
        const int cb = kt & 1;
        if (kt < qt) {                        // stage tile kt+1 into other buf
            *(short8*)&Ks[cb ^ 1][soff] = rK; // vmcnt wait is 1 tile old
            *(short8*)&Vt[cb ^ 1][soff] = rV;
            if (kt + 1 < qt) {                // issue tile kt+2 loads
                gK += (size_t)64 * 512;
                gV += 64;
                rK = *(const short8*)gK;
                rV = *(const short8*)gV;
            }
        }

        // ---- S^T strip = K(64xd) . Q^T : lane holds k = tk*16+quad*4+r, q = l15
        floatx4 sacc[4][2];
        #pragma unroll
        for (int tk = 0; tk < 4; ++tk)
            #pragma unroll
            for (int tq = 0; tq < 2; ++tq)
                sacc[tk][tq] = (floatx4){0.f, 0.f, 0.f, 0.f};
        __builtin_amdgcn_s_setprio(1);
        #pragma unroll
        for (int tk = 0; tk < 4; ++tk) {
            short8 kf0 = *(short8*)&Ks[cb][(tk * 16 + l15) * LDH + c0];
            short8 kf1 = *(short8*)&Ks[cb][(tk * 16 + l15) * LDH + c1];
            #pragma unroll
            for (int tq = 0; tq < 2; ++tq) {
                sacc[tk][tq] = __builtin_amdgcn_mfma_f32_16x16x32_bf16(kf0, qf[tq][0], sacc[tk][tq], 0, 0, 0);
                sacc[tk][tq] = __builtin_amdgcn_mfma_f32_16x16x32_bf16(kf1, qf[tq][1], sacc[tk][tq], 0, 0, 0);
            }
        }
        __builtin_amdgcn_s_setprio(0);

        if (kt == qt) {
            #pragma unroll
            for (int tk = 0; tk < 4; ++tk)
                #pragma unroll
                for (int tq = 0; tq < 2; ++tq) {
                    const int qloc = whalf * 32 + tq * 16 + l15;
                    #pragma unroll
                    for (int r = 0; r < 4; ++r)
                        if (tk * 16 + quad * 4 + r > qloc) sacc[tk][tq][r] = -INFINITY;
                }
        }

        // ---- P = exp(S') via native __expf; accumulate l per-lane
        #pragma unroll
        for (int tk = 0; tk < 4; ++tk)
            #pragma unroll
            for (int tq = 0; tq < 2; ++tq) {
                float p0 = __expf(sacc[tk][tq][0]);
                float p1 = __expf(sacc[tk][tq][1]);
                float p2 = __expf(sacc[tk][tq][2]);
                float p3 = __expf(sacc[tk][tq][3]);
                l_part[tq] += (p0 + p1) + (p2 + p3);
                sacc[tk][tq][0] = p0; sacc[tk][tq][1] = p1;
                sacc[tk][tq][2] = p2; sacc[tk][tq][3] = p3;
            }
        short8 pf[2][2];
        #pragma unroll
        for (int tq = 0; tq < 2; ++tq)
            #pragma unroll
            for (int g = 0; g < 2; ++g) {
                union { short8 s; unsigned u[4]; } uf;
                uf.u[0] = cvtpk(sacc[2 * g][tq][0],     sacc[2 * g][tq][1]);
                uf.u[1] = cvtpk(sacc[2 * g][tq][2],     sacc[2 * g][tq][3]);
                uf.u[2] = cvtpk(sacc[2 * g + 1][tq][0], sacc[2 * g + 1][tq][1]);
                uf.u[3] = cvtpk(sacc[2 * g + 1][tq][2], sacc[2 * g + 1][tq][3]);
                pf[tq][g] = uf.s;
            }

        // ---- O += P . V   (A = lane-local P frags, B = permuted V^T rows)
        __builtin_amdgcn_s_setprio(1);
        #pragma unroll
        for (int db = 0; db < 4; ++db) {
            short8 vf0 = *(short8*)&Vt[cb][(db * 16 + l15) * LDH + c0];
            short8 vf1 = *(short8*)&Vt[cb][(db * 16 + l15) * LDH + c1];
            #pragma unroll
            for (int tq = 0; tq < 2; ++tq) {
                oacc[tq][db] = __builtin_amdgcn_mfma_f32_16x16x32_bf16(pf[tq][0], vf0, oacc[tq][db], 0, 0, 0);
                oacc[tq][db] = __builtin_amdgcn_mfma_f32_16x16x32_bf16(pf[tq][1], vf1, oacc[tq][db], 0, 0, 0);
            }
        }
        __builtin_amdgcn_s_setprio(0);

        __syncthreads();                      // single barrier per K-tile
    }

    #pragma unroll
    for (int off = 16; off < 64; off <<= 1) {
        l_part[0] += __shfl_xor(l_part[0], off, 64);
        l_part[1] += __shfl_xor(l_part[1], off, 64);
    }

    #pragma unroll
    for (int tq = 0; tq < 2; ++tq)
        #pragma unroll
        for (int r = 0; r < 4; ++r) {
            const float denom = __shfl(l_part[tq], quad * 4 + r, 64);
            const float inv = 1.0f / denom;
            const int row = qt * 64 + whalf * 32 + tq * 16 + quad * 4 + r;
            #pragma unroll
            for (int db = 0; db < 4; ++db)
                ctx[((size_t)(b * TT + row) * 32 + h) * 64 + db * 16 + l15] =
                    f2bf(oacc[tq][db][r] * inv);
        }
}

extern "C" void kernel_launch(void* const* d_in, const int* in_sizes, int n_in,
                              void* d_out, int out_size, void* d_ws, size_t ws_size,
                              hipStream_t stream) {
    const float* x    = (const float*)d_in[0];
    const float* Wq   = (const float*)d_in[1];
    const float* Wk   = (const float*)d_in[2];
    const float* Wv   = (const float*)d_in[3];
    const float* Wo   = (const float*)d_in[4];
    const float* bout = (const float*)d_in[5];
    float* out = (float*)d_out;

    // workspace (shorts): xb | WqkvT | WoT | qb | kb | vb(T) | ctx | tables
    short* xb    = (short*)d_ws;
    short* WqkvT = xb + (size_t)8388608;
    short* WoT   = WqkvT + (size_t)6291456;
    short* qb    = WoT + (size_t)4194304;
    short* kb    = qb + (size_t)8388608;
    short* vb    = kb + (size_t)2097152;
    short* ctx   = vb + (size_t)2097152;
    float* cosT  = (float*)(ctx + (size_t)8388608);
    float* sinT  = cosT + 65536;

    prep<<<14592, 256, 0, stream>>>(x, Wq, Wk, Wv, Wo, xb, WqkvT, WoT, cosT, sinT);

    gemm_qkv<<<dim3(12, 16), 512, 0, stream>>>(xb, WqkvT, cosT, sinT, qb, kb, vb);

    attn_mfma<<<dim3(32, 8, 2), 512, 0, stream>>>(qb, kb, vb, ctx);

    gemm_out<<<dim3(8, 32), 512, 0, stream>>>(ctx, WoT, bout, out);
}